// Round 14
// baseline (863.773 us; speedup 1.0000x reference)
//
#include <hip/hip_runtime.h>
#include <math.h>

#define TS 10
#define TD 128
#define TE 64
#define BT 8
#define NTHR 256
#define HSTR 132          // floats per Hs row: 128+4 pad
#define QSTR 68           // floats per Q/K/Vd/G/t row: 64+4 pad
#define NHROWS (TS*BT)    // 80

#define HS_FLOATS (NHROWS*HSTR)    // 10560
#define BUF_FLOATS (40*QSTR)       // 2720 (half-batch 40-row buffer)
#define P_FLOATS (BT*TS*12)        // 960
#define LDS_FLOATS (HS_FLOATS + 3*BUF_FLOATS + P_FLOATS)   // 19680 -> 78720 B (2 WG/CU)

#define INVSQRT10 0.31622776601683794f

// workspace float offsets
#define WS_POS 0          // POS[10][128]            (1280)
#define WS_Z   1280       // Z[n][c][j] 10x4x128     (5120)
#define WS_LW  6400       // LW[p][c][e] 3x4x64      (768)
#define WS_PW  7168       // PW[p][n][e] 3x10x64     (1920)
#define WS_ZW  9088       // ZW[n][c][e] 10x4x64     (2560) -> total 11648 (46.6 KB)

typedef float v2f __attribute__((ext_vector_type(2)));

// Broadcast-free packed FMA via VOP3P op_sel (bit-identical IEEE fp32 fma),
// R7-proven; keeps the deep-prefetch gemm spill-free at the 128-VGPR cap.
#define PKFMA_LO(acc_, ap_, wp_) \
    asm("v_pk_fma_f32 %0, %1, %2, %0 op_sel:[0,0,0] op_sel_hi:[0,1,1]" \
        : "+v"(acc_) : "v"(ap_), "v"(wp_))
#define PKFMA_HI(acc_, ap_, wp_) \
    asm("v_pk_fma_f32 %0, %1, %2, %0 op_sel:[1,0,0] op_sel_hi:[1,1,1]" \
        : "+v"(acc_) : "v"(ap_), "v"(wp_))

// Wave-synchronous LDS fence (R8/R13-validated): sufficient for same-wave
// LDS RAW deps; replaces __syncthreads inside the wave-local attention chain.
#define WSYNC() do { __builtin_amdgcn_wave_barrier(); \
    asm volatile("s_waitcnt lgkmcnt(0)" ::: "memory"); \
    __builtin_amdgcn_wave_barrier(); } while (0)

// ---------------- pre-kernel (once per launch, into d_ws) -------------------
// POS (fp64, reference-exact); LW/PW (rank-4 layer-1 QKV fold, R11);
// P2->Z (layer-2 ques+UL fold, R9); ZW (layer-2 DE fold, R12-validated):
//   ZW[n][c][e] = sum_j WVu2[e][j] * Z[n][c][j]   (10 KB table)
// so out[b][n][c] = h2[b][n].Z[n][c] + s * G2[b][n].ZW[n][c] — DE-l2 deleted.
__global__ void pre_kernel(float* __restrict__ ws,
                           const float* __restrict__ L_w,
                           const float* __restrict__ WQ,
                           const float* __restrict__ WK,
                           const float* __restrict__ WVd,
                           const float* __restrict__ qin2,
                           const float* __restrict__ qout2,
                           const float* __restrict__ UL_w,
                           const float* __restrict__ WVu2) {
    __shared__ float sPOS[TS * TD];      // 1280
    __shared__ float sP2[TS * 4 * TE];   // 2560
    __shared__ float sZ[TS * 4 * TD];    // 5120 (35.8 KB total)
    const int tid = threadIdx.x;

    // POS (fp64, matches reference constant table)
    for (int idx = tid; idx < TS * TD; idx += 256) {
        int n = idx / TD, d = idx % TD;
        int j = d >> 1;
        double ang = (double)n / pow(1000.0, 2.0 * (double)j / (double)TD);
        float v = (float)((d & 1) ? cos(ang) : sin(ang));
        sPOS[idx] = v;
        ws[WS_POS + idx] = v;
    }
    // P2[n][c][i] = sum_d qout2[n][i][d]*UL_w[d][c]
    for (int idx = tid; idx < TS * 4 * TE; idx += 256) {
        int n = idx >> 8, r = idx & 255, c = r >> 6, i = r & 63;
        const float* qp = qout2 + ((size_t)n * TE + i) * TD;
        float acc = 0.f;
        for (int d = 0; d < TD; d += 4) {
            float4 q4 = *(const float4*)(qp + d);
            acc = fmaf(q4.x, UL_w[(d + 0) * 4 + c], acc);
            acc = fmaf(q4.y, UL_w[(d + 1) * 4 + c], acc);
            acc = fmaf(q4.z, UL_w[(d + 2) * 4 + c], acc);
            acc = fmaf(q4.w, UL_w[(d + 3) * 4 + c], acc);
        }
        sP2[idx] = acc;
    }
    // LW[p][c][e] (rank-4 layer-1 QKV fold)
    for (int idx = tid; idx < 3 * 4 * TE; idx += 256) {
        int p = idx >> 8, r = idx & 255, c = r >> 6, e = r & 63;
        const float* Wp = (p == 0 ? WQ : (p == 1 ? WK : WVd));
        const float* lr = L_w + c * TD;
        float acc = 0.f;
        for (int d = 0; d < TD; d++) acc = fmaf(lr[d], Wp[d * TE + e], acc);
        ws[WS_LW + idx] = acc;
    }
    __syncthreads();
    // PW[p][n][e] (reads sPOS)
    for (int idx = tid; idx < 3 * TS * TE; idx += 256) {
        int p = idx / 640, r = idx % 640, n = r >> 6, e = r & 63;
        const float* Wp = (p == 0 ? WQ : (p == 1 ? WK : WVd));
        const float* pr = sPOS + n * TD;
        float acc = 0.f;
        for (int d = 0; d < TD; d++) acc = fmaf(pr[d], Wp[d * TE + e], acc);
        ws[WS_PW + idx] = acc;
    }
    // Z[n][c][j] = sum_i qin2[n][j][i]*P2[n][c][i]  (reads sP2)
    for (int idx = tid; idx < TS * 4 * TD; idx += 256) {
        int n = idx >> 9, r = idx & 511, c = r >> 7, j = r & 127;
        const float* ip = qin2 + ((size_t)n * TD + j) * TE;
        const float* pp = sP2 + (n * 4 + c) * TE;
        float acc = 0.f;
        for (int i = 0; i < TE; i += 4) {
            float4 q4 = *(const float4*)(ip + i);
            acc = fmaf(q4.x, pp[i + 0], acc);
            acc = fmaf(q4.y, pp[i + 1], acc);
            acc = fmaf(q4.z, pp[i + 2], acc);
            acc = fmaf(q4.w, pp[i + 3], acc);
        }
        sZ[idx] = acc;
        ws[WS_Z + idx] = acc;
    }
    __syncthreads();
    // ZW[n][c][e] = sum_j WVu2[e][j]*Z[n][c][j]  (reads sZ)
    for (int idx = tid; idx < TS * 4 * TE; idx += 256) {
        int n = idx >> 8, r = idx & 255, c = r >> 6, e = r & 63;
        const float* wp = WVu2 + (size_t)e * TD;
        const float* zp = sZ + (n * 4 + c) * TD;
        float acc = 0.f;
        for (int j = 0; j < TD; j += 4) {
            float4 w4 = *(const float4*)(wp + j);
            acc = fmaf(w4.x, zp[j + 0], acc);
            acc = fmaf(w4.y, zp[j + 1], acc);
            acc = fmaf(w4.z, zp[j + 2], acc);
            acc = fmaf(w4.w, zp[j + 3], acc);
        }
        ws[WS_ZW + idx] = acc;
    }
}

// ---------------- M-row x C-col fp32 GEMM tile, packed-pair FMAs ------------
// Deep W-prefetch (R5/R6) + op_sel pk-fma (R7): spill-free at cap 128.
template <int M, int SPLIT, int C, int K, bool ADD>
__device__ __forceinline__ void gemm_f32(
    const float* __restrict__ Ap, int a0, int aHi, int aLo,
    const float* __restrict__ W, int ws,
    float* __restrict__ Op, int o0, int oHi, int oLo,
    float scale)
{
    static_assert(C % 4 == 0, "C must be a multiple of 4");
    static_assert(K % 16 == 0 && K >= 32, "K must be a multiple of 16, >=32");
    constexpr int CG = C / 4;   // float4 groups
    constexpr int CP = C / 2;   // float2 pairs
    v2f acc[M][CP];
#pragma unroll
    for (int m = 0; m < M; m++)
#pragma unroll
        for (int p = 0; p < CP; p++) acc[m][p] = (v2f)(0.f);

    float4 aR0[M], aR1[M];
    float4 wA[8 * CG], wB[8 * CG];      // ping-pong 8-k W buffers
    const float* ap = Ap + a0;
    const float* wp = W;

    auto loadW8 = [&](float4* wR, const float* w) {
#pragma unroll
        for (int kk = 0; kk < 8; kk++)
#pragma unroll
            for (int cg = 0; cg < CG; cg++)
                wR[kk * CG + cg] = *(const float4*)(w + kk * ws + cg * 4);
    };
    auto loadA = [&](float4* aR, const float* a) {
#pragma unroll
        for (int m = 0; m < M; m++)
            aR[m] = *(const float4*)(a + (m / SPLIT) * aHi + (m % SPLIT) * aLo);
    };
    auto computeH = [&](const float4* aR, const float4* wR) {
#pragma unroll
        for (int m = 0; m < M; m++) {
            const v2f* ap2 = (const v2f*)&aR[m];    // (a0,a1),(a2,a3)
#pragma unroll
            for (int kp = 0; kp < 2; kp++) {
                const v2f* wf0 = (const v2f*)&wR[(2 * kp + 0) * CG];
                const v2f* wf1 = (const v2f*)&wR[(2 * kp + 1) * CG];
#pragma unroll
                for (int p = 0; p < CP; p++) {
                    PKFMA_LO(acc[m][p], ap2[kp], wf0[p]);   // k = 2kp
                    PKFMA_HI(acc[m][p], ap2[kp], wf1[p]);   // k = 2kp+1
                }
            }
        }
    };

    loadW8(wA, wp);
    loadA(aR0, ap);
#pragma unroll 1
    for (int k = 0; k + 16 < K; k += 16) {
        loadW8(wB, wp + 8 * ws);
        loadA(aR1, ap + 4);
        computeH(aR0, wA);
        loadA(aR0, ap + 8);
        computeH(aR1, wA + 4 * CG);
        loadW8(wA, wp + 16 * ws);
        loadA(aR1, ap + 12);
        computeH(aR0, wB);
        loadA(aR0, ap + 16);
        computeH(aR1, wB + 4 * CG);
        wp += 16 * ws; ap += 16;
    }
    loadW8(wB, wp + 8 * ws);
    loadA(aR1, ap + 4);
    computeH(aR0, wA);
    loadA(aR0, ap + 8);
    computeH(aR1, wA + 4 * CG);
    loadA(aR1, ap + 12);
    computeH(aR0, wB);
    computeH(aR1, wB + 4 * CG);

    v2f s2; s2.x = scale; s2.y = scale;
#pragma unroll
    for (int m = 0; m < M; m++) {
        float* op = Op + o0 + (m / SPLIT) * oHi + (m % SPLIT) * oLo;
#pragma unroll
        for (int cg = 0; cg < CG; cg++) {
            float4 r;
            v2f* rp = (v2f*)&r;
            if constexpr (ADD) {
                float4 v = *(float4*)(op + cg * 4);
                const v2f* vp = (const v2f*)&v;
                rp[0] = s2 * acc[m][cg * 2 + 0] + vp[0];
                rp[1] = s2 * acc[m][cg * 2 + 1] + vp[1];
            } else {
                rp[0] = s2 * acc[m][cg * 2 + 0];
                rp[1] = s2 * acc[m][cg * 2 + 1];
            }
            *(float4*)(op + cg * 4) = r;
        }
    }
}

// ---------------- fused kernel ----------------------------------------------
// R14 = R13 + layer-2 DE fold through Z:
//   out[b][n][c] = h2[b][n].Z[n][c] + INVSQRT10 * G2[b][n].ZW[n][c]
// DE-l2 gemm deleted (-13% of per-WG MACs, -1 barrier/hb); out moves inside
// the hb loop (wave-local: G2 lives per-hb in Qb). R12 lesson respected:
// the fold table (ZW, 10 KB) is small — no working-set blowup.
// BT=8, 78.72 KB LDS -> 2 WG/CU; VGPR<=128 (cliff at 128/129, R5);
// launch_bounds(256,2) pins the cap (R0/R6/R7/R10/R11-proven).
extern "C" __global__ __launch_bounds__(NTHR, 2)
void trans_fused(const float* __restrict__ x,
                 const float* __restrict__ L_w, const float* __restrict__ UL_w,
                 const float* __restrict__ WQ,  const float* __restrict__ WK,
                 const float* __restrict__ WVd, const float* __restrict__ WVu,
                 const float* __restrict__ WQ2, const float* __restrict__ WK2,
                 const float* __restrict__ WVd2,const float* __restrict__ WVu2,
                 const float* __restrict__ qin1,const float* __restrict__ qout1,
                 const float* __restrict__ qin2,const float* __restrict__ qout2,
                 const float* __restrict__ POSb, float* __restrict__ out)
{
    extern __shared__ float lds[];
    float* Hs = lds;                      // [80][HSTR], row = b*10 + n
    float* Qb = lds + HS_FLOATS;          // [40][QSTR]; also G, t(lo)
    float* Kb = Qb + BUF_FLOATS;          // [40][QSTR]; also t(hi)
    float* Vb = Kb + BUF_FLOATS;          // [40][QSTR] Vd
    float* Pb = Vb + BUF_FLOATS;          // [8][10][12] logits -> softmax weights
    float* Tb = Qb;                       // t: 80 rows spanning Qb+Kb

    const int tid = threadIdx.x;
    const int vtid = (tid + ((blockIdx.x & 3) << 6)) & 255;  // rotate idle windows
    const int w = vtid >> 6;              // wave-local batch index b4 (wave-aligned)
    const int l = vtid & 63;
    const int gb0 = blockIdx.x * BT;
    const float* Zb  = POSb + WS_Z;
    const float* LWb = POSb + WS_LW;
    const float* PWb = POSb + WS_PW;
    const float* ZWb = POSb + WS_ZW;

    // ---- Phase 0: h = x @ L_w + POS ----
    for (int idx = tid; idx < NHROWS * 32; idx += NTHR) {
        int r = idx >> 5, dg = (idx & 31) << 2;
        int b = r / 10, n = r - b * 10;
        const float* xp = x + ((size_t)(gb0 + b) * TS + n) * 4;
        float4 xv = *(const float4*)xp;
        const float* xf = (const float*)&xv;
        float4 p4 = *(const float4*)(POSb + n * TD + dg);
        v2f acc0 = ((const v2f*)&p4)[0], acc1 = ((const v2f*)&p4)[1];
#pragma unroll
        for (int c = 0; c < 4; c++) {
            float4 lw = *(const float4*)(L_w + c * TD + dg);
            v2f xb; xb.x = xf[c]; xb.y = xf[c];
            acc0 = xb * ((const v2f*)&lw)[0] + acc0;
            acc1 = xb * ((const v2f*)&lw)[1] + acc1;
        }
        float4 r4;
        ((v2f*)&r4)[0] = acc0; ((v2f*)&r4)[1] = acc1;
        *(float4*)(Hs + r * HSTR + dg) = r4;
    }
    __syncthreads();

    for (int layer = 0; layer < 2; ++layer) {
        const float* pWQ  = layer ? WQ2  : WQ;
        const float* pWK  = layer ? WK2  : WK;
        const float* pWVd = layer ? WVd2 : WVd;

        for (int hb = 0; hb < 2; ++hb) {
            // batches b = hb*4 + b4; Hs rows (hb*4+b4)*10 + n
            if (layer == 0) {
                // ---- QKV layer-1, rank-4 factored: Q = x@LW + PW; 1920 tasks ----
                for (int t = vtid; t < 1920; t += NTHR) {
                    int p = t / 640, r2 = t % 640, rr = r2 >> 4, e4 = r2 & 15;
                    int b4 = rr / 10, n = rr - b4 * 10;
                    const float* xp = x + ((size_t)(gb0 + hb * 4 + b4) * TS + n) * 4;
                    float4 x4 = *(const float4*)xp;
                    const float* xf = (const float*)&x4;
                    const float* lw = LWb + p * 256 + e4 * 4;
                    float4 pw = *(const float4*)(PWb + p * 640 + n * 64 + e4 * 4);
                    v2f a0 = ((const v2f*)&pw)[0], a1 = ((const v2f*)&pw)[1];
#pragma unroll
                    for (int c = 0; c < 4; c++) {
                        float4 l4 = *(const float4*)(lw + c * 64);
                        v2f xb; xb.x = xf[c]; xb.y = xf[c];
                        a0 = xb * ((const v2f*)&l4)[0] + a0;
                        a1 = xb * ((const v2f*)&l4)[1] + a1;
                    }
                    float* Ob = (p == 0 ? Qb : (p == 1 ? Kb : Vb));
                    float4 r4;
                    ((v2f*)&r4)[0] = a0; ((v2f*)&r4)[1] = a1;
                    *(float4*)(Ob + rr * QSTR + e4 * 4) = r4;
                }
            } else {
                // ---- QKV layer-2: full-rank gemm, 240 tasks; M=8 ----
                if (vtid < 240) {
                    int p = vtid / 80, t2 = vtid % 80;
                    int np = t2 >> 4, cg = t2 & 15;
                    const float* Wp = (p == 0 ? pWQ : (p == 1 ? pWK : pWVd)) + cg * 4;
                    float* Ob = (p == 0 ? Qb : (p == 1 ? Kb : Vb));
                    gemm_f32<8, 2, 4, TD, false>(
                        Hs, (hb * 40 + np) * HSTR, 10 * HSTR, 5 * HSTR,
                        Wp, TE,
                        Ob, np * QSTR + cg * 4, 10 * QSTR, 5 * QSTR, 1.f);
                }
            }
            __syncthreads();

            // ======== wave-local chain: b4 == wave id, WSYNC joins ========
            // ---- logits: 55 (i,j<=i) pairs, one lane each; own batch ----
            if (l < 55) {
                int i = 0, base = 0, pr = l;
                while (pr >= base + i + 1) { base += i + 1; i++; }
                int j = pr - base;
                const float* qr = Qb + (w * 10 + i) * QSTR;
                const float* kr = Kb + (w * 10 + j) * QSTR;
                v2f s0 = (v2f)(0.f), s1 = (v2f)(0.f);
                for (int e = 0; e < TE; e += 8) {
                    float4 qa = *(const float4*)(qr + e);
                    float4 ka = *(const float4*)(kr + e);
                    float4 qc = *(const float4*)(qr + e + 4);
                    float4 kc = *(const float4*)(kr + e + 4);
                    s0 = ((const v2f*)&qa)[0] * ((const v2f*)&ka)[0] + s0;
                    s1 = ((const v2f*)&qa)[1] * ((const v2f*)&ka)[1] + s1;
                    s0 = ((const v2f*)&qc)[0] * ((const v2f*)&kc)[0] + s0;
                    s1 = ((const v2f*)&qc)[1] * ((const v2f*)&kc)[1] + s1;
                }
                Pb[(hb * 4 + w) * 120 + i * 12 + j] = (s0.x + s0.y) + (s1.x + s1.y);
            }
            WSYNC();

            // ---- softmax over keys j<=i (own batch) ----
            if (l < TS) {
                float* pr = Pb + (hb * 4 + w) * 120 + l * 12;
                float m = pr[0];
#pragma unroll
                for (int j = 1; j < TS; j++) if (j <= l) m = fmaxf(m, pr[j]);
                float sum = 0.f;
#pragma unroll
                for (int j = 0; j < TS; j++) if (j <= l) { float e = expf(pr[j] - m); pr[j] = e; sum += e; }
#pragma unroll
                for (int j = 0; j < TS; j++) pr[j] = (j <= l) ? pr[j] / sum : 0.f;
            }
            WSYNC();

            // ---- G[q][e] (own batch): 160 tasks per wave; into Qb (Q dead) ----
            for (int oi = l; oi < 160; oi += 64) {
                int q = oi >> 4, e4 = (oi & 15) * 4;
                const float* pp = Pb + (hb * 4 + w) * 120 + q * 12;
                v2f g0 = (v2f)(0.f), g1 = (v2f)(0.f);
#pragma unroll
                for (int k = 0; k < TS; k++) {
                    float p = pp[k];
                    v2f pv; pv.x = p; pv.y = p;
                    float4 v = *(const float4*)(Vb + (w * 10 + k) * QSTR + e4);
                    g0 = pv * ((const v2f*)&v)[0] + g0;
                    g1 = pv * ((const v2f*)&v)[1] + g1;
                }
                float4 g;
                ((v2f*)&g)[0] = g0; ((v2f*)&g)[1] = g1;
                *(float4*)(Qb + (w * 10 + q) * QSTR + e4) = g;
            }
            WSYNC();

            if (layer == 0) {
                // ---- DE: Hs(own batch) += invsqrt10 * G @ WVu; 64 tasks/wave ----
                int qp = l >> 5, cg = l & 31;
                gemm_f32<5, 5, 4, TE, true>(
                    Qb, (w * 10 + qp * 5) * QSTR, 0, QSTR,
                    WVu + cg * 4, TD,
                    Hs, (hb * 40 + w * 10 + qp * 5) * HSTR + cg * 4, 0, HSTR,
                    INVSQRT10);
            } else {
                // ---- out (fold of DE-l2 + E22.Z): wave-local, 40 tasks/wave ----
                // out[b][n][c] = h2[b][n].Z[n][c] + s * G2[b][n].ZW[n][c]
                if (l < 40) {
                    int n = l >> 2, c = l & 3;
                    const float* hr = Hs + (hb * 40 + w * 10 + n) * HSTR;
                    const float* zr = Zb + (n * 4 + c) * TD;
                    v2f s0 = (v2f)(0.f), s1 = (v2f)(0.f);
                    for (int d = 0; d < TD; d += 8) {
                        float4 ha = *(const float4*)(hr + d);
                        float4 za = *(const float4*)(zr + d);
                        float4 hc = *(const float4*)(hr + d + 4);
                        float4 zc = *(const float4*)(zr + d + 4);
                        s0 = ((const v2f*)&ha)[0] * ((const v2f*)&za)[0] + s0;
                        s1 = ((const v2f*)&ha)[1] * ((const v2f*)&za)[1] + s1;
                        s0 = ((const v2f*)&hc)[0] * ((const v2f*)&zc)[0] + s0;
                        s1 = ((const v2f*)&hc)[1] * ((const v2f*)&zc)[1] + s1;
                    }
                    float base = (s0.x + s0.y) + (s1.x + s1.y);
                    const float* gr = Qb + (w * 10 + n) * QSTR;
                    const float* zw = ZWb + (n * 4 + c) * TE;
                    v2f a0 = (v2f)(0.f), a1 = (v2f)(0.f);
                    for (int e = 0; e < TE; e += 8) {
                        float4 ga = *(const float4*)(gr + e);
                        float4 za = *(const float4*)(zw + e);
                        float4 gc = *(const float4*)(gr + e + 4);
                        float4 zc = *(const float4*)(zw + e + 4);
                        a0 = ((const v2f*)&ga)[0] * ((const v2f*)&za)[0] + a0;
                        a1 = ((const v2f*)&ga)[1] * ((const v2f*)&za)[1] + a1;
                        a0 = ((const v2f*)&gc)[0] * ((const v2f*)&zc)[0] + a0;
                        a1 = ((const v2f*)&gc)[1] * ((const v2f*)&zc)[1] + a1;
                    }
                    float att = (a0.x + a0.y) + (a1.x + a1.y);
                    out[((size_t)(gb0 + hb * 4 + w) * TS + n) * 4 + c] =
                        base + att * INVSQRT10;
                }
            }
            __syncthreads();
        } // hb

        if (layer == 0) {
            // ---- ques-in: t[80][64] = Hs @ quesin1[n]; 160 tasks M=8 ----
            if (vtid < 160) {
                int n = vtid >> 4, cg = vtid & 15;
                gemm_f32<8, 1, 4, TD, false>(
                    Hs, n * HSTR, 10 * HSTR, 0,
                    qin1 + (size_t)n * TD * TE + cg * 4, TE,
                    Tb, n * QSTR + cg * 4, 10 * QSTR, 0, 1.f);
            }
            __syncthreads();

            // ---- ques-out: Hs = t @ quesout1[n]; 320 tasks M=8 C=4 ----
            for (int task = vtid; task < 320; task += NTHR) {
                int n = task >> 5, cg = task & 31;
                gemm_f32<8, 1, 4, TE, false>(
                    Tb, n * QSTR, 10 * QSTR, 0,
                    qout1 + (size_t)n * TE * TD + cg * 4, TD,
                    Hs, n * HSTR + cg * 4, 10 * HSTR, 0, 1.f);
            }
            __syncthreads();
        }
        // layer 1: out already written inside the hb loop
    } // layer
}

// ---------------- host launch -----------------------------------------------
extern "C" void kernel_launch(void* const* d_in, const int* in_sizes, int n_in,
                              void* d_out, int out_size, void* d_ws, size_t ws_size,
                              hipStream_t stream) {
    const float* x    = (const float*)d_in[0];
    const float* L_w  = (const float*)d_in[1];
    const float* UL_w = (const float*)d_in[2];
    const float* WQ   = (const float*)d_in[3];
    const float* WK   = (const float*)d_in[4];
    const float* WVd  = (const float*)d_in[5];
    const float* WVu  = (const float*)d_in[6];
    const float* WQ2  = (const float*)d_in[7];
    const float* WK2  = (const float*)d_in[8];
    const float* WVd2 = (const float*)d_in[9];
    const float* WVu2 = (const float*)d_in[10];
    const float* qin1 = (const float*)d_in[11];
    const float* qout1= (const float*)d_in[12];
    const float* qin2 = (const float*)d_in[13];
    const float* qout2= (const float*)d_in[14];
    float* out = (float*)d_out;
    float* POSb = (float*)d_ws;   // WS_* layout (46.6 KB)

    int B = in_sizes[0] / (TS * 4);
    size_t lds_bytes = (size_t)LDS_FLOATS * sizeof(float);

    (void)hipFuncSetAttribute((const void*)trans_fused,
                              hipFuncAttributeMaxDynamicSharedMemorySize,
                              (int)lds_bytes);

    pre_kernel<<<dim3(1), dim3(256), 0, stream>>>(POSb, L_w, WQ, WK, WVd,
                                                  qin2, qout2, UL_w, WVu2);
    trans_fused<<<dim3(B / BT), dim3(NTHR), lds_bytes, stream>>>(
        x, L_w, UL_w, WQ, WK, WVd, WVu, WQ2, WK2, WVd2, WVu2,
        qin1, qout1, qin2, qout2, POSb, out);
}

// Round 15
// 799.791 us; speedup vs baseline: 1.0800x; 1.0800x over previous
//
#include <hip/hip_runtime.h>
#include <math.h>

#define TS 10
#define TD 128
#define TE 64
#define BT 8
#define NTHR 256
#define HSTR 132          // floats per Hs row: 128+4 pad
#define QSTR 68           // floats per Q/K/Vd/G/t row: 64+4 pad
#define NHROWS (TS*BT)    // 80

#define HS_FLOATS (NHROWS*HSTR)    // 10560
#define BUF_FLOATS (40*QSTR)       // 2720 (half-batch 40-row buffer)
#define P_FLOATS (BT*TS*12)        // 960
#define LDS_FLOATS (HS_FLOATS + 3*BUF_FLOATS + P_FLOATS)   // 19680 -> 78720 B (2 WG/CU)

#define INVSQRT10 0.31622776601683794f

// workspace float offsets
#define WS_POS   0        // POS[10][128]            (1280)
#define WS_Z     1280     // Z[n][c][j] 10x4x128     (5120)
#define WS_LW    6400     // LW[p][c][e] 3x4x64      (768)
#define WS_PW    7168     // PW[p][n][e] 3x10x64     (1920)
#define WS_ZW    9088     // ZW[n][c][e] 10x4x64     (2560)
#define WS_LQ    11648    // LQ[n][c][k] 10x4x64     (2560)
#define WS_PQ    14208    // PQ[n][k]    10x64       (640)
#define WS_WVUQ  14848    // WVuQ[n][e][k] 10x64x64  (40960) -> total 55808 (223 KB)

typedef float v2f __attribute__((ext_vector_type(2)));

// Broadcast-free packed FMA via VOP3P op_sel (bit-identical IEEE fp32 fma),
// R7-proven; keeps the deep-prefetch gemm spill-free at the 128-VGPR cap.
#define PKFMA_LO(acc_, ap_, wp_) \
    asm("v_pk_fma_f32 %0, %1, %2, %0 op_sel:[0,0,0] op_sel_hi:[0,1,1]" \
        : "+v"(acc_) : "v"(ap_), "v"(wp_))
#define PKFMA_HI(acc_, ap_, wp_) \
    asm("v_pk_fma_f32 %0, %1, %2, %0 op_sel:[1,0,0] op_sel_hi:[1,1,1]" \
        : "+v"(acc_) : "v"(ap_), "v"(wp_))

// Wave-synchronous LDS fence (R8/R13-validated): sufficient for same-wave
// LDS RAW deps; replaces __syncthreads inside the wave-local attention chain.
#define WSYNC() do { __builtin_amdgcn_wave_barrier(); \
    asm volatile("s_waitcnt lgkmcnt(0)" ::: "memory"); \
    __builtin_amdgcn_wave_barrier(); } while (0)

// ---------------- pre-kernel (once per launch, into d_ws) -------------------
// 11 blocks. Block 0: POS (fp64, reference-exact); LW/PW (rank-4 layer-1 QKV
// fold, R11); P2->Z (layer-2 ques+UL fold, R9); ZW (layer-2 DE fold, R14);
// LQ/PQ (NEW, layer-1 t1 fold):
//   LQ[n][c][k] = sum_d L_w[c][d]*qin1[n][d][k]
//   PQ[n][k]    = sum_d POS[n][d]*qin1[n][d][k]
// Blocks 1..10: WVuQ[n][e][k] = sum_d WVu[e][d]*qin1[n][d][k]  (160 KB)
// With these, t1 = x@LQ + PQ + s*(G1@WVuQ): Phase-0, DE-l1 and quesin1 are
// all deleted from the main kernel (-24% FLOPs, -390KB/WG streaming gross).
__global__ void pre_kernel(float* __restrict__ ws,
                           const float* __restrict__ L_w,
                           const float* __restrict__ WQ,
                           const float* __restrict__ WK,
                           const float* __restrict__ WVd,
                           const float* __restrict__ qin2,
                           const float* __restrict__ qout2,
                           const float* __restrict__ UL_w,
                           const float* __restrict__ WVu2,
                           const float* __restrict__ qin1,
                           const float* __restrict__ WVu) {
    const int tid = threadIdx.x;
    const int bid = blockIdx.x;

    if (bid > 0) {   // WVuQ[n], one n per block
        int n = bid - 1;
        float* dst = ws + WS_WVUQ + n * 4096;
        for (int idx = tid; idx < TE * TE; idx += 256) {
            int e = idx >> 6, k = idx & 63;
            const float* wv = WVu + (size_t)e * TD;
            const float* qp = qin1 + (size_t)n * TD * TE + k;
            float acc = 0.f;
            for (int d = 0; d < TD; d++) acc = fmaf(wv[d], qp[d * TE], acc);
            dst[idx] = acc;
        }
        return;
    }

    __shared__ float sPOS[TS * TD];      // 1280
    __shared__ float sP2[TS * 4 * TE];   // 2560
    __shared__ float sZ[TS * 4 * TD];    // 5120 (35.8 KB total)

    // POS (fp64, matches reference constant table)
    for (int idx = tid; idx < TS * TD; idx += 256) {
        int n = idx / TD, d = idx % TD;
        int j = d >> 1;
        double ang = (double)n / pow(1000.0, 2.0 * (double)j / (double)TD);
        float v = (float)((d & 1) ? cos(ang) : sin(ang));
        sPOS[idx] = v;
        ws[WS_POS + idx] = v;
    }
    // P2[n][c][i] = sum_d qout2[n][i][d]*UL_w[d][c]
    for (int idx = tid; idx < TS * 4 * TE; idx += 256) {
        int n = idx >> 8, r = idx & 255, c = r >> 6, i = r & 63;
        const float* qp = qout2 + ((size_t)n * TE + i) * TD;
        float acc = 0.f;
        for (int d = 0; d < TD; d += 4) {
            float4 q4 = *(const float4*)(qp + d);
            acc = fmaf(q4.x, UL_w[(d + 0) * 4 + c], acc);
            acc = fmaf(q4.y, UL_w[(d + 1) * 4 + c], acc);
            acc = fmaf(q4.z, UL_w[(d + 2) * 4 + c], acc);
            acc = fmaf(q4.w, UL_w[(d + 3) * 4 + c], acc);
        }
        sP2[idx] = acc;
    }
    // LW[p][c][e] (rank-4 layer-1 QKV fold)
    for (int idx = tid; idx < 3 * 4 * TE; idx += 256) {
        int p = idx >> 8, r = idx & 255, c = r >> 6, e = r & 63;
        const float* Wp = (p == 0 ? WQ : (p == 1 ? WK : WVd));
        const float* lr = L_w + c * TD;
        float acc = 0.f;
        for (int d = 0; d < TD; d++) acc = fmaf(lr[d], Wp[d * TE + e], acc);
        ws[WS_LW + idx] = acc;
    }
    __syncthreads();
    // PW[p][n][e] (reads sPOS)
    for (int idx = tid; idx < 3 * TS * TE; idx += 256) {
        int p = idx / 640, r = idx % 640, n = r >> 6, e = r & 63;
        const float* Wp = (p == 0 ? WQ : (p == 1 ? WK : WVd));
        const float* pr = sPOS + n * TD;
        float acc = 0.f;
        for (int d = 0; d < TD; d++) acc = fmaf(pr[d], Wp[d * TE + e], acc);
        ws[WS_PW + idx] = acc;
    }
    // LQ[n][c][k] = sum_d L_w[c][d]*qin1[n][d][k]
    for (int idx = tid; idx < TS * 4 * TE; idx += 256) {
        int n = idx >> 8, r = idx & 255, c = r >> 6, k = r & 63;
        const float* lr = L_w + c * TD;
        const float* qp = qin1 + (size_t)n * TD * TE + k;
        float acc = 0.f;
        for (int d = 0; d < TD; d++) acc = fmaf(lr[d], qp[d * TE], acc);
        ws[WS_LQ + idx] = acc;
    }
    // PQ[n][k] = sum_d POS[n][d]*qin1[n][d][k]  (reads sPOS)
    for (int idx = tid; idx < TS * TE; idx += 256) {
        int n = idx >> 6, k = idx & 63;
        const float* pr = sPOS + n * TD;
        const float* qp = qin1 + (size_t)n * TD * TE + k;
        float acc = 0.f;
        for (int d = 0; d < TD; d++) acc = fmaf(pr[d], qp[d * TE], acc);
        ws[WS_PQ + idx] = acc;
    }
    // Z[n][c][j] = sum_i qin2[n][j][i]*P2[n][c][i]  (reads sP2)
    for (int idx = tid; idx < TS * 4 * TD; idx += 256) {
        int n = idx >> 9, r = idx & 511, c = r >> 7, j = r & 127;
        const float* ip = qin2 + ((size_t)n * TD + j) * TE;
        const float* pp = sP2 + (n * 4 + c) * TE;
        float acc = 0.f;
        for (int i = 0; i < TE; i += 4) {
            float4 q4 = *(const float4*)(ip + i);
            acc = fmaf(q4.x, pp[i + 0], acc);
            acc = fmaf(q4.y, pp[i + 1], acc);
            acc = fmaf(q4.z, pp[i + 2], acc);
            acc = fmaf(q4.w, pp[i + 3], acc);
        }
        sZ[idx] = acc;
        ws[WS_Z + idx] = acc;
    }
    __syncthreads();
    // ZW[n][c][e] = sum_j WVu2[e][j]*Z[n][c][j]  (reads sZ)
    for (int idx = tid; idx < TS * 4 * TE; idx += 256) {
        int n = idx >> 8, r = idx & 255, c = r >> 6, e = r & 63;
        const float* wp = WVu2 + (size_t)e * TD;
        const float* zp = sZ + (n * 4 + c) * TD;
        float acc = 0.f;
        for (int j = 0; j < TD; j += 4) {
            float4 w4 = *(const float4*)(wp + j);
            acc = fmaf(w4.x, zp[j + 0], acc);
            acc = fmaf(w4.y, zp[j + 1], acc);
            acc = fmaf(w4.z, zp[j + 2], acc);
            acc = fmaf(w4.w, zp[j + 3], acc);
        }
        ws[WS_ZW + idx] = acc;
    }
}

// ---------------- M-row x C-col fp32 GEMM tile, packed-pair FMAs ------------
// Deep W-prefetch (R5/R6) + op_sel pk-fma (R7): spill-free at cap 128.
template <int M, int SPLIT, int C, int K, bool ADD>
__device__ __forceinline__ void gemm_f32(
    const float* __restrict__ Ap, int a0, int aHi, int aLo,
    const float* __restrict__ W, int ws,
    float* __restrict__ Op, int o0, int oHi, int oLo,
    float scale)
{
    static_assert(C % 4 == 0, "C must be a multiple of 4");
    static_assert(K % 16 == 0 && K >= 32, "K must be a multiple of 16, >=32");
    constexpr int CG = C / 4;   // float4 groups
    constexpr int CP = C / 2;   // float2 pairs
    v2f acc[M][CP];
#pragma unroll
    for (int m = 0; m < M; m++)
#pragma unroll
        for (int p = 0; p < CP; p++) acc[m][p] = (v2f)(0.f);

    float4 aR0[M], aR1[M];
    float4 wA[8 * CG], wB[8 * CG];      // ping-pong 8-k W buffers
    const float* ap = Ap + a0;
    const float* wp = W;

    auto loadW8 = [&](float4* wR, const float* w) {
#pragma unroll
        for (int kk = 0; kk < 8; kk++)
#pragma unroll
            for (int cg = 0; cg < CG; cg++)
                wR[kk * CG + cg] = *(const float4*)(w + kk * ws + cg * 4);
    };
    auto loadA = [&](float4* aR, const float* a) {
#pragma unroll
        for (int m = 0; m < M; m++)
            aR[m] = *(const float4*)(a + (m / SPLIT) * aHi + (m % SPLIT) * aLo);
    };
    auto computeH = [&](const float4* aR, const float4* wR) {
#pragma unroll
        for (int m = 0; m < M; m++) {
            const v2f* ap2 = (const v2f*)&aR[m];    // (a0,a1),(a2,a3)
#pragma unroll
            for (int kp = 0; kp < 2; kp++) {
                const v2f* wf0 = (const v2f*)&wR[(2 * kp + 0) * CG];
                const v2f* wf1 = (const v2f*)&wR[(2 * kp + 1) * CG];
#pragma unroll
                for (int p = 0; p < CP; p++) {
                    PKFMA_LO(acc[m][p], ap2[kp], wf0[p]);   // k = 2kp
                    PKFMA_HI(acc[m][p], ap2[kp], wf1[p]);   // k = 2kp+1
                }
            }
        }
    };

    loadW8(wA, wp);
    loadA(aR0, ap);
#pragma unroll 1
    for (int k = 0; k + 16 < K; k += 16) {
        loadW8(wB, wp + 8 * ws);
        loadA(aR1, ap + 4);
        computeH(aR0, wA);
        loadA(aR0, ap + 8);
        computeH(aR1, wA + 4 * CG);
        loadW8(wA, wp + 16 * ws);
        loadA(aR1, ap + 12);
        computeH(aR0, wB);
        loadA(aR0, ap + 16);
        computeH(aR1, wB + 4 * CG);
        wp += 16 * ws; ap += 16;
    }
    loadW8(wB, wp + 8 * ws);
    loadA(aR1, ap + 4);
    computeH(aR0, wA);
    loadA(aR0, ap + 8);
    computeH(aR1, wA + 4 * CG);
    loadA(aR1, ap + 12);
    computeH(aR0, wB);
    computeH(aR1, wB + 4 * CG);

    v2f s2; s2.x = scale; s2.y = scale;
#pragma unroll
    for (int m = 0; m < M; m++) {
        float* op = Op + o0 + (m / SPLIT) * oHi + (m % SPLIT) * oLo;
#pragma unroll
        for (int cg = 0; cg < CG; cg++) {
            float4 r;
            v2f* rp = (v2f*)&r;
            if constexpr (ADD) {
                float4 v = *(float4*)(op + cg * 4);
                const v2f* vp = (const v2f*)&v;
                rp[0] = s2 * acc[m][cg * 2 + 0] + vp[0];
                rp[1] = s2 * acc[m][cg * 2 + 1] + vp[1];
            } else {
                rp[0] = s2 * acc[m][cg * 2 + 0];
                rp[1] = s2 * acc[m][cg * 2 + 1];
            }
            *(float4*)(op + cg * 4) = r;
        }
    }
}

// ---------------- fused kernel ----------------------------------------------
// R15 = R14 + qin1 fold: t1 = x@LQ + PQ + s*(G1@WVuQ[n]). Phase-0, DE-l1 and
// quesin1 deleted (-24% MACs; table +320KB vs -390KB deleted streaming).
// t1 parks in Hs cols 0..63 (Hs free until quesout1), copied to Tb, then
// quesout1 + layer-2 run as in R14 (ZW out-fold).
// BT=8, 78.72 KB LDS -> 2 WG/CU; VGPR<=128 (cliff at 128/129, R5);
// launch_bounds(256,2) pins the cap (R0/R6/R7/R10/R11-proven).
extern "C" __global__ __launch_bounds__(NTHR, 2)
void trans_fused(const float* __restrict__ x,
                 const float* __restrict__ L_w, const float* __restrict__ UL_w,
                 const float* __restrict__ WQ,  const float* __restrict__ WK,
                 const float* __restrict__ WVd, const float* __restrict__ WVu,
                 const float* __restrict__ WQ2, const float* __restrict__ WK2,
                 const float* __restrict__ WVd2,const float* __restrict__ WVu2,
                 const float* __restrict__ qin1,const float* __restrict__ qout1,
                 const float* __restrict__ qin2,const float* __restrict__ qout2,
                 const float* __restrict__ POSb, float* __restrict__ out)
{
    extern __shared__ float lds[];
    float* Hs = lds;                      // [80][HSTR]; t1 (cols 0..63) then h2
    float* Qb = lds + HS_FLOATS;          // [40][QSTR]; also G, t(lo)
    float* Kb = Qb + BUF_FLOATS;          // [40][QSTR]; also t(hi)
    float* Vb = Kb + BUF_FLOATS;          // [40][QSTR] Vd
    float* Pb = Vb + BUF_FLOATS;          // [8][10][12] logits -> softmax weights
    float* Tb = Qb;                       // t1: 80 rows spanning Qb+Kb

    const int tid = threadIdx.x;
    const int vtid = (tid + ((blockIdx.x & 3) << 6)) & 255;  // rotate idle windows
    const int w = vtid >> 6;              // wave-local batch index b4 (wave-aligned)
    const int l = vtid & 63;
    const int gb0 = blockIdx.x * BT;
    const float* Zb    = POSb + WS_Z;
    const float* LWb   = POSb + WS_LW;
    const float* PWb   = POSb + WS_PW;
    const float* ZWb   = POSb + WS_ZW;
    const float* LQb   = POSb + WS_LQ;
    const float* PQb   = POSb + WS_PQ;
    const float* WVuQb = POSb + WS_WVUQ;

    // ================= LAYER 1 (h never materialized) =================
    for (int hb = 0; hb < 2; ++hb) {
        // ---- QKV-l1 rank-4 (1920 tasks) + t1base = x@LQ + PQ (640 tasks) ----
        for (int t = vtid; t < 2560; t += NTHR) {
            if (t < 1920) {
                int p = t / 640, r2 = t % 640, rr = r2 >> 4, e4 = r2 & 15;
                int b4 = rr / 10, n = rr - b4 * 10;
                const float* xp = x + ((size_t)(gb0 + hb * 4 + b4) * TS + n) * 4;
                float4 x4 = *(const float4*)xp;
                const float* xf = (const float*)&x4;
                const float* lw = LWb + p * 256 + e4 * 4;
                float4 pw = *(const float4*)(PWb + p * 640 + n * 64 + e4 * 4);
                v2f a0 = ((const v2f*)&pw)[0], a1 = ((const v2f*)&pw)[1];
#pragma unroll
                for (int c = 0; c < 4; c++) {
                    float4 l4 = *(const float4*)(lw + c * 64);
                    v2f xb; xb.x = xf[c]; xb.y = xf[c];
                    a0 = xb * ((const v2f*)&l4)[0] + a0;
                    a1 = xb * ((const v2f*)&l4)[1] + a1;
                }
                float* Ob = (p == 0 ? Qb : (p == 1 ? Kb : Vb));
                float4 r4;
                ((v2f*)&r4)[0] = a0; ((v2f*)&r4)[1] = a1;
                *(float4*)(Ob + rr * QSTR + e4 * 4) = r4;
            } else {
                int t2 = t - 1920;              // 0..639
                int rr = t2 >> 4, cg = t2 & 15;
                int b4 = rr / 10, n = rr - b4 * 10;
                const float* xp = x + ((size_t)(gb0 + hb * 4 + b4) * TS + n) * 4;
                float4 x4 = *(const float4*)xp;
                const float* xf = (const float*)&x4;
                const float* lq = LQb + n * 256 + cg * 4;
                float4 pq = *(const float4*)(PQb + n * 64 + cg * 4);
                v2f a0 = ((const v2f*)&pq)[0], a1 = ((const v2f*)&pq)[1];
#pragma unroll
                for (int c = 0; c < 4; c++) {
                    float4 l4 = *(const float4*)(lq + c * 64);
                    v2f xb; xb.x = xf[c]; xb.y = xf[c];
                    a0 = xb * ((const v2f*)&l4)[0] + a0;
                    a1 = xb * ((const v2f*)&l4)[1] + a1;
                }
                float4 r4;
                ((v2f*)&r4)[0] = a0; ((v2f*)&r4)[1] = a1;
                *(float4*)(Hs + (hb * 40 + rr) * HSTR + cg * 4) = r4;
            }
        }
        __syncthreads();

        // ---- logits: 55 (i,j<=i) pairs, one lane each; own batch ----
        if (l < 55) {
            int i = 0, base = 0, pr = l;
            while (pr >= base + i + 1) { base += i + 1; i++; }
            int j = pr - base;
            const float* qr = Qb + (w * 10 + i) * QSTR;
            const float* kr = Kb + (w * 10 + j) * QSTR;
            v2f s0 = (v2f)(0.f), s1 = (v2f)(0.f);
            for (int e = 0; e < TE; e += 8) {
                float4 qa = *(const float4*)(qr + e);
                float4 ka = *(const float4*)(kr + e);
                float4 qc = *(const float4*)(qr + e + 4);
                float4 kc = *(const float4*)(kr + e + 4);
                s0 = ((const v2f*)&qa)[0] * ((const v2f*)&ka)[0] + s0;
                s1 = ((const v2f*)&qa)[1] * ((const v2f*)&ka)[1] + s1;
                s0 = ((const v2f*)&qc)[0] * ((const v2f*)&kc)[0] + s0;
                s1 = ((const v2f*)&qc)[1] * ((const v2f*)&kc)[1] + s1;
            }
            Pb[(hb * 4 + w) * 120 + i * 12 + j] = (s0.x + s0.y) + (s1.x + s1.y);
        }
        WSYNC();

        // ---- softmax over keys j<=i (own batch) ----
        if (l < TS) {
            float* pr = Pb + (hb * 4 + w) * 120 + l * 12;
            float m = pr[0];
#pragma unroll
            for (int j = 1; j < TS; j++) if (j <= l) m = fmaxf(m, pr[j]);
            float sum = 0.f;
#pragma unroll
            for (int j = 0; j < TS; j++) if (j <= l) { float e = expf(pr[j] - m); pr[j] = e; sum += e; }
#pragma unroll
            for (int j = 0; j < TS; j++) pr[j] = (j <= l) ? pr[j] / sum : 0.f;
        }
        WSYNC();

        // ---- G[q][e] (own batch): 160 tasks per wave; into Qb (Q dead) ----
        for (int oi = l; oi < 160; oi += 64) {
            int q = oi >> 4, e4 = (oi & 15) * 4;
            const float* pp = Pb + (hb * 4 + w) * 120 + q * 12;
            v2f g0 = (v2f)(0.f), g1 = (v2f)(0.f);
#pragma unroll
            for (int k = 0; k < TS; k++) {
                float p = pp[k];
                v2f pv; pv.x = p; pv.y = p;
                float4 v = *(const float4*)(Vb + (w * 10 + k) * QSTR + e4);
                g0 = pv * ((const v2f*)&v)[0] + g0;
                g1 = pv * ((const v2f*)&v)[1] + g1;
            }
            float4 g;
            ((v2f*)&g)[0] = g0; ((v2f*)&g)[1] = g1;
            *(float4*)(Qb + (w * 10 + q) * QSTR + e4) = g;
        }
        __syncthreads();   // t1gemm groups rows across waves (M=4 over b4)

        // ---- t1 += s * G @ WVuQ[n]: 160 tasks = n(10) x cg(16), M=4, K=64 ----
        if (vtid < 160) {
            int n = vtid >> 4, cg = vtid & 15;
            gemm_f32<4, 1, 4, TE, true>(
                Qb, n * QSTR, 10 * QSTR, 0,
                WVuQb + n * 4096 + cg * 4, TE,
                Hs, (hb * 40 + n) * HSTR + cg * 4, 10 * HSTR, 0,
                INVSQRT10);
        }
        __syncthreads();
    } // hb layer 1

    // ---- copy t1 (Hs cols 0..63, 80 rows) -> Tb (Qb/Kb free) ----
    for (int t = vtid; t < 1280; t += NTHR) {
        int r = t >> 4, q4 = (t & 15) << 2;
        *(float4*)(Tb + r * QSTR + q4) = *(const float4*)(Hs + r * HSTR + q4);
    }
    __syncthreads();

    // ---- quesout1: h2 = t1 @ qout1[n] -> Hs; 320 tasks M=8 C=4 K=64 ----
    for (int task = vtid; task < 320; task += NTHR) {
        int n = task >> 5, cg = task & 31;
        gemm_f32<8, 1, 4, TE, false>(
            Tb, n * QSTR, 10 * QSTR, 0,
            qout1 + (size_t)n * TE * TD + cg * 4, TD,
            Hs, n * HSTR + cg * 4, 10 * HSTR, 0, 1.f);
    }
    __syncthreads();

    // ================= LAYER 2 (R14 form: ZW out-fold) =================
    for (int hb = 0; hb < 2; ++hb) {
        // ---- QKV-l2: full-rank gemm, 240 tasks; M=8 K=128 ----
        if (vtid < 240) {
            int p = vtid / 80, t2 = vtid % 80;
            int np = t2 >> 4, cg = t2 & 15;
            const float* Wp = (p == 0 ? WQ2 : (p == 1 ? WK2 : WVd2)) + cg * 4;
            float* Ob = (p == 0 ? Qb : (p == 1 ? Kb : Vb));
            gemm_f32<8, 2, 4, TD, false>(
                Hs, (hb * 40 + np) * HSTR, 10 * HSTR, 5 * HSTR,
                Wp, TE,
                Ob, np * QSTR + cg * 4, 10 * QSTR, 5 * QSTR, 1.f);
        }
        __syncthreads();

        // ---- logits2 (wave-local) ----
        if (l < 55) {
            int i = 0, base = 0, pr = l;
            while (pr >= base + i + 1) { base += i + 1; i++; }
            int j = pr - base;
            const float* qr = Qb + (w * 10 + i) * QSTR;
            const float* kr = Kb + (w * 10 + j) * QSTR;
            v2f s0 = (v2f)(0.f), s1 = (v2f)(0.f);
            for (int e = 0; e < TE; e += 8) {
                float4 qa = *(const float4*)(qr + e);
                float4 ka = *(const float4*)(kr + e);
                float4 qc = *(const float4*)(qr + e + 4);
                float4 kc = *(const float4*)(kr + e + 4);
                s0 = ((const v2f*)&qa)[0] * ((const v2f*)&ka)[0] + s0;
                s1 = ((const v2f*)&qa)[1] * ((const v2f*)&ka)[1] + s1;
                s0 = ((const v2f*)&qc)[0] * ((const v2f*)&kc)[0] + s0;
                s1 = ((const v2f*)&qc)[1] * ((const v2f*)&kc)[1] + s1;
            }
            Pb[(hb * 4 + w) * 120 + i * 12 + j] = (s0.x + s0.y) + (s1.x + s1.y);
        }
        WSYNC();

        // ---- softmax2 (own batch) ----
        if (l < TS) {
            float* pr = Pb + (hb * 4 + w) * 120 + l * 12;
            float m = pr[0];
#pragma unroll
            for (int j = 1; j < TS; j++) if (j <= l) m = fmaxf(m, pr[j]);
            float sum = 0.f;
#pragma unroll
            for (int j = 0; j < TS; j++) if (j <= l) { float e = expf(pr[j] - m); pr[j] = e; sum += e; }
#pragma unroll
            for (int j = 0; j < TS; j++) pr[j] = (j <= l) ? pr[j] / sum : 0.f;
        }
        WSYNC();

        // ---- G2[q][e] (own batch): 160 tasks/wave; into Qb (Q2 dead) ----
        for (int oi = l; oi < 160; oi += 64) {
            int q = oi >> 4, e4 = (oi & 15) * 4;
            const float* pp = Pb + (hb * 4 + w) * 120 + q * 12;
            v2f g0 = (v2f)(0.f), g1 = (v2f)(0.f);
#pragma unroll
            for (int k = 0; k < TS; k++) {
                float p = pp[k];
                v2f pv; pv.x = p; pv.y = p;
                float4 v = *(const float4*)(Vb + (w * 10 + k) * QSTR + e4);
                g0 = pv * ((const v2f*)&v)[0] + g0;
                g1 = pv * ((const v2f*)&v)[1] + g1;
            }
            float4 g;
            ((v2f*)&g)[0] = g0; ((v2f*)&g)[1] = g1;
            *(float4*)(Qb + (w * 10 + q) * QSTR + e4) = g;
        }
        WSYNC();

        // ---- out-fold: out[b][n][c] = h2.Z[n][c] + s * G2.ZW[n][c] ----
        if (l < 40) {
            int n = l >> 2, c = l & 3;
            const float* hr = Hs + (hb * 40 + w * 10 + n) * HSTR;
            const float* zr = Zb + (n * 4 + c) * TD;
            v2f s0 = (v2f)(0.f), s1 = (v2f)(0.f);
            for (int d = 0; d < TD; d += 8) {
                float4 ha = *(const float4*)(hr + d);
                float4 za = *(const float4*)(zr + d);
                float4 hc = *(const float4*)(hr + d + 4);
                float4 zc = *(const float4*)(zr + d + 4);
                s0 = ((const v2f*)&ha)[0] * ((const v2f*)&za)[0] + s0;
                s1 = ((const v2f*)&ha)[1] * ((const v2f*)&za)[1] + s1;
                s0 = ((const v2f*)&hc)[0] * ((const v2f*)&zc)[0] + s0;
                s1 = ((const v2f*)&hc)[1] * ((const v2f*)&zc)[1] + s1;
            }
            float base = (s0.x + s0.y) + (s1.x + s1.y);
            const float* gr = Qb + (w * 10 + n) * QSTR;
            const float* zw = ZWb + (n * 4 + c) * TE;
            v2f a0 = (v2f)(0.f), a1 = (v2f)(0.f);
            for (int e = 0; e < TE; e += 8) {
                float4 ga = *(const float4*)(gr + e);
                float4 za = *(const float4*)(zw + e);
                float4 gc = *(const float4*)(gr + e + 4);
                float4 zc = *(const float4*)(zw + e + 4);
                a0 = ((const v2f*)&ga)[0] * ((const v2f*)&za)[0] + a0;
                a1 = ((const v2f*)&ga)[1] * ((const v2f*)&za)[1] + a1;
                a0 = ((const v2f*)&gc)[0] * ((const v2f*)&zc)[0] + a0;
                a1 = ((const v2f*)&gc)[1] * ((const v2f*)&zc)[1] + a1;
            }
            float att = (a0.x + a0.y) + (a1.x + a1.y);
            out[((size_t)(gb0 + hb * 4 + w) * TS + n) * 4 + c] =
                base + att * INVSQRT10;
        }
        __syncthreads();
    } // hb layer 2
}

// ---------------- host launch -----------------------------------------------
extern "C" void kernel_launch(void* const* d_in, const int* in_sizes, int n_in,
                              void* d_out, int out_size, void* d_ws, size_t ws_size,
                              hipStream_t stream) {
    const float* x    = (const float*)d_in[0];
    const float* L_w  = (const float*)d_in[1];
    const float* UL_w = (const float*)d_in[2];
    const float* WQ   = (const float*)d_in[3];
    const float* WK   = (const float*)d_in[4];
    const float* WVd  = (const float*)d_in[5];
    const float* WVu  = (const float*)d_in[6];
    const float* WQ2  = (const float*)d_in[7];
    const float* WK2  = (const float*)d_in[8];
    const float* WVd2 = (const float*)d_in[9];
    const float* WVu2 = (const float*)d_in[10];
    const float* qin1 = (const float*)d_in[11];
    const float* qout1= (const float*)d_in[12];
    const float* qin2 = (const float*)d_in[13];
    const float* qout2= (const float*)d_in[14];
    float* out = (float*)d_out;
    float* POSb = (float*)d_ws;   // WS_* layout (223 KB)

    int B = in_sizes[0] / (TS * 4);
    size_t lds_bytes = (size_t)LDS_FLOATS * sizeof(float);

    (void)hipFuncSetAttribute((const void*)trans_fused,
                              hipFuncAttributeMaxDynamicSharedMemorySize,
                              (int)lds_bytes);

    pre_kernel<<<dim3(11), dim3(256), 0, stream>>>(
        POSb, L_w, WQ, WK, WVd, qin2, qout2, UL_w, WVu2, qin1, WVu);
    trans_fused<<<dim3(B / BT), dim3(NTHR), lds_bytes, stream>>>(
        x, L_w, UL_w, WQ, WK, WVd, WVu, WQ2, WK2, WVd2, WVu2,
        qin1, qout1, qin2, qout2, POSb, out);
}

// Round 16
// 699.245 us; speedup vs baseline: 1.2353x; 1.1438x over previous
//
#include <hip/hip_runtime.h>
#include <math.h>

#define TS 10
#define TD 128
#define TE 64
#define BT 8
#define NTHR 256
#define HSTR 132          // floats per Hs row: 128+4 pad (t1 lives in cols 0..63)
#define QSTR 68           // floats per Q/K/Vd/G row: 64+4 pad
#define NHROWS (TS*BT)    // 80

#define HS_FLOATS (NHROWS*HSTR)    // 10560
#define BUF_FLOATS (40*QSTR)       // 2720 (half-batch 40-row buffer)
#define P_FLOATS (BT*TS*12)        // 960
#define LDS_FLOATS (HS_FLOATS + 3*BUF_FLOATS + P_FLOATS)   // 19680 -> 78720 B (2 WG/CU)

#define INVSQRT10 0.31622776601683794f

// workspace float offsets
#define WS_POS   0        // POS[10][128]             (1280)
#define WS_Z     1280     // Z[n][c][j] 10x4x128      (5120)
#define WS_LW    6400     // LW[p][c][e] 3x4x64       (768)
#define WS_PW    7168     // PW[p][n][e] 3x10x64      (1920)
#define WS_ZW    9088     // ZW[n][c][e] 10x4x64      (2560)
#define WS_LQ    11648    // LQ[n][c][k] 10x4x64      (2560)
#define WS_PQ    14208    // PQ[n][k]    10x64        (640)
#define WS_ZQ    14848    // ZQ[n][c][k] 10x4x64      (2560)
#define WS_WVUQ  17408    // WVuQ[n][e][k] 10x64x64   (40960)
#define WS_W2N   58368    // W2N[p][n][k][e] 3x10x64x64 (122880) -> end 181248 (725 KB)

typedef float v2f __attribute__((ext_vector_type(2)));

// Broadcast-free packed FMA via VOP3P op_sel (bit-identical IEEE fp32 fma),
// R7-proven; keeps the deep-prefetch gemm spill-free at the 128-VGPR cap.
#define PKFMA_LO(acc_, ap_, wp_) \
    asm("v_pk_fma_f32 %0, %1, %2, %0 op_sel:[0,0,0] op_sel_hi:[0,1,1]" \
        : "+v"(acc_) : "v"(ap_), "v"(wp_))
#define PKFMA_HI(acc_, ap_, wp_) \
    asm("v_pk_fma_f32 %0, %1, %2, %0 op_sel:[1,0,0] op_sel_hi:[1,1,1]" \
        : "+v"(acc_) : "v"(ap_), "v"(wp_))

// Wave-synchronous LDS fence (R8/R13-validated): sufficient for same-wave
// LDS RAW deps; replaces __syncthreads inside the wave-local attention chain.
#define WSYNC() do { __builtin_amdgcn_wave_barrier(); \
    asm volatile("s_waitcnt lgkmcnt(0)" ::: "memory"); \
    __builtin_amdgcn_wave_barrier(); } while (0)

// ---------------- pre-kernel (once per launch, into d_ws) -------------------
// 41 blocks. Block 0: POS (fp64, reference-exact); LW/PW (rank-4 l1-QKV fold,
// R11); P2->Z (l2 ques+UL fold, R9); ZW (l2 DE fold, R14); LQ/PQ (l1 t1 fold,
// R15); ZQ (NEW in main path; R12-validated): ZQ[n][c][k]=sum_j qout1[n][k][j]
// *Z[n][c][j] -> out's h2.Z becomes t1.ZQ, h2 never materialized.
// Blocks 1..10: WVuQ[n][e][k] = sum_d WVu[e][d]*qin1[n][d][k] (R15).
// Blocks 11..40: W2N[p][n][k][e] = sum_j qout1[n][k][j]*W{Q2,K2,Vd2}[j][e]
// (R12-validated) -> QKV-l2 runs on t1 at K=64; quesout1 deleted.
__global__ void pre_kernel(float* __restrict__ ws,
                           const float* __restrict__ L_w,
                           const float* __restrict__ WQ,
                           const float* __restrict__ WK,
                           const float* __restrict__ WVd,
                           const float* __restrict__ qin2,
                           const float* __restrict__ qout2,
                           const float* __restrict__ UL_w,
                           const float* __restrict__ WVu2,
                           const float* __restrict__ qin1,
                           const float* __restrict__ WVu,
                           const float* __restrict__ qout1,
                           const float* __restrict__ WQ2,
                           const float* __restrict__ WK2,
                           const float* __restrict__ WVd2) {
    const int tid = threadIdx.x;
    const int bid = blockIdx.x;

    if (bid >= 11) {   // W2N tables, one (p,n) per block
        int p = (bid - 11) / 10, n = (bid - 11) % 10;
        const float* Wp = (p == 0 ? WQ2 : (p == 1 ? WK2 : WVd2));
        float* dst = ws + WS_W2N + ((p * 10 + n) << 12);
        for (int idx = tid; idx < TE * TE; idx += 256) {
            int k = idx >> 6, e = idx & 63;
            const float* qp = qout1 + ((size_t)n * TE + k) * TD;
            float acc = 0.f;
            for (int j = 0; j < TD; j += 4) {
                float4 q4 = *(const float4*)(qp + j);
                acc = fmaf(q4.x, Wp[(j + 0) * TE + e], acc);
                acc = fmaf(q4.y, Wp[(j + 1) * TE + e], acc);
                acc = fmaf(q4.z, Wp[(j + 2) * TE + e], acc);
                acc = fmaf(q4.w, Wp[(j + 3) * TE + e], acc);
            }
            dst[idx] = acc;
        }
        return;
    }
    if (bid > 0) {     // WVuQ[n], one n per block
        int n = bid - 1;
        float* dst = ws + WS_WVUQ + n * 4096;
        for (int idx = tid; idx < TE * TE; idx += 256) {
            int e = idx >> 6, k = idx & 63;
            const float* wv = WVu + (size_t)e * TD;
            const float* qp = qin1 + (size_t)n * TD * TE + k;
            float acc = 0.f;
            for (int d = 0; d < TD; d++) acc = fmaf(wv[d], qp[d * TE], acc);
            dst[idx] = acc;
        }
        return;
    }

    __shared__ float sPOS[TS * TD];      // 1280
    __shared__ float sP2[TS * 4 * TE];   // 2560
    __shared__ float sZ[TS * 4 * TD];    // 5120 (35.8 KB total)

    // POS (fp64, matches reference constant table)
    for (int idx = tid; idx < TS * TD; idx += 256) {
        int n = idx / TD, d = idx % TD;
        int j = d >> 1;
        double ang = (double)n / pow(1000.0, 2.0 * (double)j / (double)TD);
        float v = (float)((d & 1) ? cos(ang) : sin(ang));
        sPOS[idx] = v;
        ws[WS_POS + idx] = v;
    }
    // P2[n][c][i] = sum_d qout2[n][i][d]*UL_w[d][c]
    for (int idx = tid; idx < TS * 4 * TE; idx += 256) {
        int n = idx >> 8, r = idx & 255, c = r >> 6, i = r & 63;
        const float* qp = qout2 + ((size_t)n * TE + i) * TD;
        float acc = 0.f;
        for (int d = 0; d < TD; d += 4) {
            float4 q4 = *(const float4*)(qp + d);
            acc = fmaf(q4.x, UL_w[(d + 0) * 4 + c], acc);
            acc = fmaf(q4.y, UL_w[(d + 1) * 4 + c], acc);
            acc = fmaf(q4.z, UL_w[(d + 2) * 4 + c], acc);
            acc = fmaf(q4.w, UL_w[(d + 3) * 4 + c], acc);
        }
        sP2[idx] = acc;
    }
    // LW[p][c][e] (rank-4 layer-1 QKV fold)
    for (int idx = tid; idx < 3 * 4 * TE; idx += 256) {
        int p = idx >> 8, r = idx & 255, c = r >> 6, e = r & 63;
        const float* Wp = (p == 0 ? WQ : (p == 1 ? WK : WVd));
        const float* lr = L_w + c * TD;
        float acc = 0.f;
        for (int d = 0; d < TD; d++) acc = fmaf(lr[d], Wp[d * TE + e], acc);
        ws[WS_LW + idx] = acc;
    }
    __syncthreads();
    // PW[p][n][e] (reads sPOS)
    for (int idx = tid; idx < 3 * TS * TE; idx += 256) {
        int p = idx / 640, r = idx % 640, n = r >> 6, e = r & 63;
        const float* Wp = (p == 0 ? WQ : (p == 1 ? WK : WVd));
        const float* pr = sPOS + n * TD;
        float acc = 0.f;
        for (int d = 0; d < TD; d++) acc = fmaf(pr[d], Wp[d * TE + e], acc);
        ws[WS_PW + idx] = acc;
    }
    // LQ[n][c][k] = sum_d L_w[c][d]*qin1[n][d][k]
    for (int idx = tid; idx < TS * 4 * TE; idx += 256) {
        int n = idx >> 8, r = idx & 255, c = r >> 6, k = r & 63;
        const float* lr = L_w + c * TD;
        const float* qp = qin1 + (size_t)n * TD * TE + k;
        float acc = 0.f;
        for (int d = 0; d < TD; d++) acc = fmaf(lr[d], qp[d * TE], acc);
        ws[WS_LQ + idx] = acc;
    }
    // PQ[n][k] = sum_d POS[n][d]*qin1[n][d][k]  (reads sPOS)
    for (int idx = tid; idx < TS * TE; idx += 256) {
        int n = idx >> 6, k = idx & 63;
        const float* pr = sPOS + n * TD;
        const float* qp = qin1 + (size_t)n * TD * TE + k;
        float acc = 0.f;
        for (int d = 0; d < TD; d++) acc = fmaf(pr[d], qp[d * TE], acc);
        ws[WS_PQ + idx] = acc;
    }
    // Z[n][c][j] = sum_i qin2[n][j][i]*P2[n][c][i]  (reads sP2)
    for (int idx = tid; idx < TS * 4 * TD; idx += 256) {
        int n = idx >> 9, r = idx & 511, c = r >> 7, j = r & 127;
        const float* ip = qin2 + ((size_t)n * TD + j) * TE;
        const float* pp = sP2 + (n * 4 + c) * TE;
        float acc = 0.f;
        for (int i = 0; i < TE; i += 4) {
            float4 q4 = *(const float4*)(ip + i);
            acc = fmaf(q4.x, pp[i + 0], acc);
            acc = fmaf(q4.y, pp[i + 1], acc);
            acc = fmaf(q4.z, pp[i + 2], acc);
            acc = fmaf(q4.w, pp[i + 3], acc);
        }
        sZ[idx] = acc;
        ws[WS_Z + idx] = acc;
    }
    __syncthreads();
    // ZW[n][c][e] = sum_j WVu2[e][j]*Z[n][c][j]  (reads sZ)
    for (int idx = tid; idx < TS * 4 * TE; idx += 256) {
        int n = idx >> 8, r = idx & 255, c = r >> 6, e = r & 63;
        const float* wp = WVu2 + (size_t)e * TD;
        const float* zp = sZ + (n * 4 + c) * TD;
        float acc = 0.f;
        for (int j = 0; j < TD; j += 4) {
            float4 w4 = *(const float4*)(wp + j);
            acc = fmaf(w4.x, zp[j + 0], acc);
            acc = fmaf(w4.y, zp[j + 1], acc);
            acc = fmaf(w4.z, zp[j + 2], acc);
            acc = fmaf(w4.w, zp[j + 3], acc);
        }
        ws[WS_ZW + idx] = acc;
    }
    // ZQ[n][c][k] = sum_j qout1[n][k][j]*Z[n][c][j]  (reads sZ)
    for (int idx = tid; idx < TS * 4 * TE; idx += 256) {
        int n = idx >> 8, r = idx & 255, c = r >> 6, k = r & 63;
        const float* qp = qout1 + ((size_t)n * TE + k) * TD;
        const float* zp = sZ + (n * 4 + c) * TD;
        float acc = 0.f;
        for (int j = 0; j < TD; j += 4) {
            float4 q4 = *(const float4*)(qp + j);
            acc = fmaf(q4.x, zp[j + 0], acc);
            acc = fmaf(q4.y, zp[j + 1], acc);
            acc = fmaf(q4.z, zp[j + 2], acc);
            acc = fmaf(q4.w, zp[j + 3], acc);
        }
        ws[WS_ZQ + idx] = acc;
    }
}

// ---------------- M-row x C-col fp32 GEMM tile, packed-pair FMAs ------------
// Deep W-prefetch (R5/R6) + op_sel pk-fma (R7): spill-free at cap 128.
template <int M, int SPLIT, int C, int K, bool ADD>
__device__ __forceinline__ void gemm_f32(
    const float* __restrict__ Ap, int a0, int aHi, int aLo,
    const float* __restrict__ W, int ws,
    float* __restrict__ Op, int o0, int oHi, int oLo,
    float scale)
{
    static_assert(C % 4 == 0, "C must be a multiple of 4");
    static_assert(K % 16 == 0 && K >= 32, "K must be a multiple of 16, >=32");
    constexpr int CG = C / 4;   // float4 groups
    constexpr int CP = C / 2;   // float2 pairs
    v2f acc[M][CP];
#pragma unroll
    for (int m = 0; m < M; m++)
#pragma unroll
        for (int p = 0; p < CP; p++) acc[m][p] = (v2f)(0.f);

    float4 aR0[M], aR1[M];
    float4 wA[8 * CG], wB[8 * CG];      // ping-pong 8-k W buffers
    const float* ap = Ap + a0;
    const float* wp = W;

    auto loadW8 = [&](float4* wR, const float* w) {
#pragma unroll
        for (int kk = 0; kk < 8; kk++)
#pragma unroll
            for (int cg = 0; cg < CG; cg++)
                wR[kk * CG + cg] = *(const float4*)(w + kk * ws + cg * 4);
    };
    auto loadA = [&](float4* aR, const float* a) {
#pragma unroll
        for (int m = 0; m < M; m++)
            aR[m] = *(const float4*)(a + (m / SPLIT) * aHi + (m % SPLIT) * aLo);
    };
    auto computeH = [&](const float4* aR, const float4* wR) {
#pragma unroll
        for (int m = 0; m < M; m++) {
            const v2f* ap2 = (const v2f*)&aR[m];    // (a0,a1),(a2,a3)
#pragma unroll
            for (int kp = 0; kp < 2; kp++) {
                const v2f* wf0 = (const v2f*)&wR[(2 * kp + 0) * CG];
                const v2f* wf1 = (const v2f*)&wR[(2 * kp + 1) * CG];
#pragma unroll
                for (int p = 0; p < CP; p++) {
                    PKFMA_LO(acc[m][p], ap2[kp], wf0[p]);   // k = 2kp
                    PKFMA_HI(acc[m][p], ap2[kp], wf1[p]);   // k = 2kp+1
                }
            }
        }
    };

    loadW8(wA, wp);
    loadA(aR0, ap);
#pragma unroll 1
    for (int k = 0; k + 16 < K; k += 16) {
        loadW8(wB, wp + 8 * ws);
        loadA(aR1, ap + 4);
        computeH(aR0, wA);
        loadA(aR0, ap + 8);
        computeH(aR1, wA + 4 * CG);
        loadW8(wA, wp + 16 * ws);
        loadA(aR1, ap + 12);
        computeH(aR0, wB);
        loadA(aR0, ap + 16);
        computeH(aR1, wB + 4 * CG);
        wp += 16 * ws; ap += 16;
    }
    loadW8(wB, wp + 8 * ws);
    loadA(aR1, ap + 4);
    computeH(aR0, wA);
    loadA(aR0, ap + 8);
    computeH(aR1, wA + 4 * CG);
    loadA(aR1, ap + 12);
    computeH(aR0, wB);
    computeH(aR1, wB + 4 * CG);

    v2f s2; s2.x = scale; s2.y = scale;
#pragma unroll
    for (int m = 0; m < M; m++) {
        float* op = Op + o0 + (m / SPLIT) * oHi + (m % SPLIT) * oLo;
#pragma unroll
        for (int cg = 0; cg < CG; cg++) {
            float4 r;
            v2f* rp = (v2f*)&r;
            if constexpr (ADD) {
                float4 v = *(float4*)(op + cg * 4);
                const v2f* vp = (const v2f*)&v;
                rp[0] = s2 * acc[m][cg * 2 + 0] + vp[0];
                rp[1] = s2 * acc[m][cg * 2 + 1] + vp[1];
            } else {
                rp[0] = s2 * acc[m][cg * 2 + 0];
                rp[1] = s2 * acc[m][cg * 2 + 1];
            }
            *(float4*)(op + cg * 4) = r;
        }
    }
}

// ---------------- fused kernel ----------------------------------------------
// R16 = R15 + rank-64 layer-2 collapse, retried with R12's confounds removed:
//   QKV-l2 = t1 @ W2N[p][n] (K=64; same L2 bytes as the K=128 form — each W
//   slice was re-read 5x across np);  quesout1 + t1-copy DELETED;
//   out = t1.ZQ[n][c] + s * G2.ZW[n][c]  (h2 never materialized).
// -46% of remaining MACs, -2 phases, -2 barriers, -320KB/WG streaming.
// t1 lives in Hs cols 0..63 through all of layer 2.
// BT=8, 78.72 KB LDS -> 2 WG/CU; VGPR<=128 (cliff at 128/129, R5);
// launch_bounds(256,2) pins the cap (R0/R6/R7/R10/R11-proven).
extern "C" __global__ __launch_bounds__(NTHR, 2)
void trans_fused(const float* __restrict__ x,
                 const float* __restrict__ L_w, const float* __restrict__ UL_w,
                 const float* __restrict__ WQ,  const float* __restrict__ WK,
                 const float* __restrict__ WVd, const float* __restrict__ WVu,
                 const float* __restrict__ WQ2, const float* __restrict__ WK2,
                 const float* __restrict__ WVd2,const float* __restrict__ WVu2,
                 const float* __restrict__ qin1,const float* __restrict__ qout1,
                 const float* __restrict__ qin2,const float* __restrict__ qout2,
                 const float* __restrict__ POSb, float* __restrict__ out)
{
    extern __shared__ float lds[];
    float* Hs = lds;                      // [80][HSTR]; t1 in cols 0..63 (persistent)
    float* Qb = lds + HS_FLOATS;          // [40][QSTR]; Q then G (per hb)
    float* Kb = Qb + BUF_FLOATS;          // [40][QSTR]
    float* Vb = Kb + BUF_FLOATS;          // [40][QSTR] Vd
    float* Pb = Vb + BUF_FLOATS;          // [8][10][12] logits -> softmax weights

    const int tid = threadIdx.x;
    const int vtid = (tid + ((blockIdx.x & 3) << 6)) & 255;  // rotate idle windows
    const int w = vtid >> 6;              // wave-local batch index b4 (wave-aligned)
    const int l = vtid & 63;
    const int gb0 = blockIdx.x * BT;
    const float* Zb    = POSb + WS_Z;     (void)Zb;
    const float* LWb   = POSb + WS_LW;
    const float* PWb   = POSb + WS_PW;
    const float* ZWb   = POSb + WS_ZW;
    const float* LQb   = POSb + WS_LQ;
    const float* PQb   = POSb + WS_PQ;
    const float* ZQb   = POSb + WS_ZQ;
    const float* WVuQb = POSb + WS_WVUQ;
    const float* W2Nb  = POSb + WS_W2N;

    // ================= LAYER 1 (h never materialized) =================
    for (int hb = 0; hb < 2; ++hb) {
        // ---- QKV-l1 rank-4 (1920 tasks) + t1base = x@LQ + PQ (640 tasks) ----
        for (int t = vtid; t < 2560; t += NTHR) {
            if (t < 1920) {
                int p = t / 640, r2 = t % 640, rr = r2 >> 4, e4 = r2 & 15;
                int b4 = rr / 10, n = rr - b4 * 10;
                const float* xp = x + ((size_t)(gb0 + hb * 4 + b4) * TS + n) * 4;
                float4 x4 = *(const float4*)xp;
                const float* xf = (const float*)&x4;
                const float* lw = LWb + p * 256 + e4 * 4;
                float4 pw = *(const float4*)(PWb + p * 640 + n * 64 + e4 * 4);
                v2f a0 = ((const v2f*)&pw)[0], a1 = ((const v2f*)&pw)[1];
#pragma unroll
                for (int c = 0; c < 4; c++) {
                    float4 l4 = *(const float4*)(lw + c * 64);
                    v2f xb; xb.x = xf[c]; xb.y = xf[c];
                    a0 = xb * ((const v2f*)&l4)[0] + a0;
                    a1 = xb * ((const v2f*)&l4)[1] + a1;
                }
                float* Ob = (p == 0 ? Qb : (p == 1 ? Kb : Vb));
                float4 r4;
                ((v2f*)&r4)[0] = a0; ((v2f*)&r4)[1] = a1;
                *(float4*)(Ob + rr * QSTR + e4 * 4) = r4;
            } else {
                int t2 = t - 1920;              // 0..639
                int rr = t2 >> 4, cg = t2 & 15;
                int b4 = rr / 10, n = rr - b4 * 10;
                const float* xp = x + ((size_t)(gb0 + hb * 4 + b4) * TS + n) * 4;
                float4 x4 = *(const float4*)xp;
                const float* xf = (const float*)&x4;
                const float* lq = LQb + n * 256 + cg * 4;
                float4 pq = *(const float4*)(PQb + n * 64 + cg * 4);
                v2f a0 = ((const v2f*)&pq)[0], a1 = ((const v2f*)&pq)[1];
#pragma unroll
                for (int c = 0; c < 4; c++) {
                    float4 l4 = *(const float4*)(lq + c * 64);
                    v2f xb; xb.x = xf[c]; xb.y = xf[c];
                    a0 = xb * ((const v2f*)&l4)[0] + a0;
                    a1 = xb * ((const v2f*)&l4)[1] + a1;
                }
                float4 r4;
                ((v2f*)&r4)[0] = a0; ((v2f*)&r4)[1] = a1;
                *(float4*)(Hs + (hb * 40 + rr) * HSTR + cg * 4) = r4;
            }
        }
        __syncthreads();

        // ---- logits: 55 (i,j<=i) pairs, one lane each; own batch ----
        if (l < 55) {
            int i = 0, base = 0, pr = l;
            while (pr >= base + i + 1) { base += i + 1; i++; }
            int j = pr - base;
            const float* qr = Qb + (w * 10 + i) * QSTR;
            const float* kr = Kb + (w * 10 + j) * QSTR;
            v2f s0 = (v2f)(0.f), s1 = (v2f)(0.f);
            for (int e = 0; e < TE; e += 8) {
                float4 qa = *(const float4*)(qr + e);
                float4 ka = *(const float4*)(kr + e);
                float4 qc = *(const float4*)(qr + e + 4);
                float4 kc = *(const float4*)(kr + e + 4);
                s0 = ((const v2f*)&qa)[0] * ((const v2f*)&ka)[0] + s0;
                s1 = ((const v2f*)&qa)[1] * ((const v2f*)&ka)[1] + s1;
                s0 = ((const v2f*)&qc)[0] * ((const v2f*)&kc)[0] + s0;
                s1 = ((const v2f*)&qc)[1] * ((const v2f*)&kc)[1] + s1;
            }
            Pb[(hb * 4 + w) * 120 + i * 12 + j] = (s0.x + s0.y) + (s1.x + s1.y);
        }
        WSYNC();

        // ---- softmax over keys j<=i (own batch) ----
        if (l < TS) {
            float* pr = Pb + (hb * 4 + w) * 120 + l * 12;
            float m = pr[0];
#pragma unroll
            for (int j = 1; j < TS; j++) if (j <= l) m = fmaxf(m, pr[j]);
            float sum = 0.f;
#pragma unroll
            for (int j = 0; j < TS; j++) if (j <= l) { float e = expf(pr[j] - m); pr[j] = e; sum += e; }
#pragma unroll
            for (int j = 0; j < TS; j++) pr[j] = (j <= l) ? pr[j] / sum : 0.f;
        }
        WSYNC();

        // ---- G[q][e] (own batch): 160 tasks per wave; into Qb (Q dead) ----
        for (int oi = l; oi < 160; oi += 64) {
            int q = oi >> 4, e4 = (oi & 15) * 4;
            const float* pp = Pb + (hb * 4 + w) * 120 + q * 12;
            v2f g0 = (v2f)(0.f), g1 = (v2f)(0.f);
#pragma unroll
            for (int k = 0; k < TS; k++) {
                float p = pp[k];
                v2f pv; pv.x = p; pv.y = p;
                float4 v = *(const float4*)(Vb + (w * 10 + k) * QSTR + e4);
                g0 = pv * ((const v2f*)&v)[0] + g0;
                g1 = pv * ((const v2f*)&v)[1] + g1;
            }
            float4 g;
            ((v2f*)&g)[0] = g0; ((v2f*)&g)[1] = g1;
            *(float4*)(Qb + (w * 10 + q) * QSTR + e4) = g;
        }
        __syncthreads();   // t1gemm groups rows across waves (M=4 over b4)

        // ---- t1 += s * G @ WVuQ[n]: 160 tasks = n(10) x cg(16), M=4, K=64 ----
        if (vtid < 160) {
            int n = vtid >> 4, cg = vtid & 15;
            gemm_f32<4, 1, 4, TE, true>(
                Qb, n * QSTR, 10 * QSTR, 0,
                WVuQb + n * 4096 + cg * 4, TE,
                Hs, (hb * 40 + n) * HSTR + cg * 4, 10 * HSTR, 0,
                INVSQRT10);
        }
        __syncthreads();
    } // hb layer 1

    // ================= LAYER 2 (rank-64 collapsed; t1 stays in Hs) ==========
    for (int hb = 0; hb < 2; ++hb) {
        // ---- QKV-l2: Q2/K2/V2 = t1 @ W2N[p][n]; 480 tasks, M=4, K=64 ----
        for (int t = vtid; t < 480; t += NTHR) {
            int p = t / 160, rem = t - p * 160, n = rem >> 4, cg = rem & 15;
            float* Ob = (p == 0 ? Qb : (p == 1 ? Kb : Vb));
            gemm_f32<4, 1, 4, TE, false>(
                Hs, (hb * 40 + n) * HSTR, 10 * HSTR, 0,
                W2Nb + ((p * 10 + n) << 12) + cg * 4, TE,
                Ob, n * QSTR + cg * 4, 10 * QSTR, 0, 1.f);
        }
        __syncthreads();

        // ---- logits2 (wave-local) ----
        if (l < 55) {
            int i = 0, base = 0, pr = l;
            while (pr >= base + i + 1) { base += i + 1; i++; }
            int j = pr - base;
            const float* qr = Qb + (w * 10 + i) * QSTR;
            const float* kr = Kb + (w * 10 + j) * QSTR;
            v2f s0 = (v2f)(0.f), s1 = (v2f)(0.f);
            for (int e = 0; e < TE; e += 8) {
                float4 qa = *(const float4*)(qr + e);
                float4 ka = *(const float4*)(kr + e);
                float4 qc = *(const float4*)(qr + e + 4);
                float4 kc = *(const float4*)(kr + e + 4);
                s0 = ((const v2f*)&qa)[0] * ((const v2f*)&ka)[0] + s0;
                s1 = ((const v2f*)&qa)[1] * ((const v2f*)&ka)[1] + s1;
                s0 = ((const v2f*)&qc)[0] * ((const v2f*)&kc)[0] + s0;
                s1 = ((const v2f*)&qc)[1] * ((const v2f*)&kc)[1] + s1;
            }
            Pb[(hb * 4 + w) * 120 + i * 12 + j] = (s0.x + s0.y) + (s1.x + s1.y);
        }
        WSYNC();

        // ---- softmax2 (own batch) ----
        if (l < TS) {
            float* pr = Pb + (hb * 4 + w) * 120 + l * 12;
            float m = pr[0];
#pragma unroll
            for (int j = 1; j < TS; j++) if (j <= l) m = fmaxf(m, pr[j]);
            float sum = 0.f;
#pragma unroll
            for (int j = 0; j < TS; j++) if (j <= l) { float e = expf(pr[j] - m); pr[j] = e; sum += e; }
#pragma unroll
            for (int j = 0; j < TS; j++) pr[j] = (j <= l) ? pr[j] / sum : 0.f;
        }
        WSYNC();

        // ---- G2[q][e] (own batch): 160 tasks/wave; into Qb (Q2 dead) ----
        for (int oi = l; oi < 160; oi += 64) {
            int q = oi >> 4, e4 = (oi & 15) * 4;
            const float* pp = Pb + (hb * 4 + w) * 120 + q * 12;
            v2f g0 = (v2f)(0.f), g1 = (v2f)(0.f);
#pragma unroll
            for (int k = 0; k < TS; k++) {
                float p = pp[k];
                v2f pv; pv.x = p; pv.y = p;
                float4 v = *(const float4*)(Vb + (w * 10 + k) * QSTR + e4);
                g0 = pv * ((const v2f*)&v)[0] + g0;
                g1 = pv * ((const v2f*)&v)[1] + g1;
            }
            float4 g;
            ((v2f*)&g)[0] = g0; ((v2f*)&g)[1] = g1;
            *(float4*)(Qb + (w * 10 + q) * QSTR + e4) = g;
        }
        WSYNC();

        // ---- out-fold: out[b][n][c] = t1.ZQ[n][c] + s * G2.ZW[n][c] ----
        if (l < 40) {
            int n = l >> 2, c = l & 3;
            const float* tr = Hs + (hb * 40 + w * 10 + n) * HSTR;   // t1 row
            const float* zq = ZQb + (n * 4 + c) * TE;
            v2f s0 = (v2f)(0.f), s1 = (v2f)(0.f);
            for (int k = 0; k < TE; k += 8) {
                float4 ta = *(const float4*)(tr + k);
                float4 za = *(const float4*)(zq + k);
                float4 tc = *(const float4*)(tr + k + 4);
                float4 zc = *(const float4*)(zq + k + 4);
                s0 = ((const v2f*)&ta)[0] * ((const v2f*)&za)[0] + s0;
                s1 = ((const v2f*)&ta)[1] * ((const v2f*)&za)[1] + s1;
                s0 = ((const v2f*)&tc)[0] * ((const v2f*)&zc)[0] + s0;
                s1 = ((const v2f*)&tc)[1] * ((const v2f*)&zc)[1] + s1;
            }
            float base = (s0.x + s0.y) + (s1.x + s1.y);
            const float* gr = Qb + (w * 10 + n) * QSTR;
            const float* zw = ZWb + (n * 4 + c) * TE;
            v2f a0 = (v2f)(0.f), a1 = (v2f)(0.f);
            for (int e = 0; e < TE; e += 8) {
                float4 ga = *(const float4*)(gr + e);
                float4 za = *(const float4*)(zw + e);
                float4 gc = *(const float4*)(gr + e + 4);
                float4 zc = *(const float4*)(zw + e + 4);
                a0 = ((const v2f*)&ga)[0] * ((const v2f*)&za)[0] + a0;
                a1 = ((const v2f*)&ga)[1] * ((const v2f*)&za)[1] + a1;
                a0 = ((const v2f*)&gc)[0] * ((const v2f*)&zc)[0] + a0;
                a1 = ((const v2f*)&gc)[1] * ((const v2f*)&zc)[1] + a1;
            }
            float att = (a0.x + a0.y) + (a1.x + a1.y);
            out[((size_t)(gb0 + hb * 4 + w) * TS + n) * 4 + c] =
                base + att * INVSQRT10;
        }
        __syncthreads();
    } // hb layer 2
}

// ---------------- host launch -----------------------------------------------
extern "C" void kernel_launch(void* const* d_in, const int* in_sizes, int n_in,
                              void* d_out, int out_size, void* d_ws, size_t ws_size,
                              hipStream_t stream) {
    const float* x    = (const float*)d_in[0];
    const float* L_w  = (const float*)d_in[1];
    const float* UL_w = (const float*)d_in[2];
    const float* WQ   = (const float*)d_in[3];
    const float* WK   = (const float*)d_in[4];
    const float* WVd  = (const float*)d_in[5];
    const float* WVu  = (const float*)d_in[6];
    const float* WQ2  = (const float*)d_in[7];
    const float* WK2  = (const float*)d_in[8];
    const float* WVd2 = (const float*)d_in[9];
    const float* WVu2 = (const float*)d_in[10];
    const float* qin1 = (const float*)d_in[11];
    const float* qout1= (const float*)d_in[12];
    const float* qin2 = (const float*)d_in[13];
    const float* qout2= (const float*)d_in[14];
    float* out = (float*)d_out;
    float* POSb = (float*)d_ws;   // WS_* layout (725 KB)

    int B = in_sizes[0] / (TS * 4);
    size_t lds_bytes = (size_t)LDS_FLOATS * sizeof(float);

    (void)hipFuncSetAttribute((const void*)trans_fused,
                              hipFuncAttributeMaxDynamicSharedMemorySize,
                              (int)lds_bytes);

    pre_kernel<<<dim3(41), dim3(256), 0, stream>>>(
        POSb, L_w, WQ, WK, WVd, qin2, qout2, UL_w, WVu2, qin1, WVu,
        qout1, WQ2, WK2, WVd2);
    trans_fused<<<dim3(B / BT), dim3(NTHR), lds_bytes, stream>>>(
        x, L_w, UL_w, WQ, WK, WVd, WVu, WQ2, WK2, WVd2, WVu2,
        qin1, qout1, qin2, qout2, POSb, out);
}

// Round 17
// 614.727 us; speedup vs baseline: 1.4051x; 1.1375x over previous
//
#include <hip/hip_runtime.h>
#include <math.h>

#define TS 10
#define TD 128
#define TE 64
#define BT 8
#define NTHR 256
#define HSTR 132          // floats per Hs row: 128+4 pad (t1 lives in cols 0..63)
#define QSTR 68           // floats per Q/K/Vd/G row: 64+4 pad
#define NHROWS (TS*BT)    // 80

#define HS_FLOATS (NHROWS*HSTR)    // 10560
#define BUF_FLOATS (40*QSTR)       // 2720 (half-batch 40-row buffer)
#define P_FLOATS (BT*TS*12)        // 960
#define LDS_FLOATS (HS_FLOATS + 3*BUF_FLOATS + P_FLOATS)   // 19680 -> 78720 B (2 WG/CU)

#define INVSQRT10 0.31622776601683794f

// workspace float offsets
#define WS_POS   0        // POS[10][128]             (1280)
#define WS_LW    1280     // LW[p][c][e] 3x4x64       (768)
#define WS_PW    2048     // PW[p][n][e] 3x10x64      (1920)
#define WS_ZW    3968     // ZW[n][c][e] 10x4x64      (2560)
#define WS_LQ    6528     // LQ[n][c][k] 10x4x64      (2560)
#define WS_PQ    9088     // PQ[n][k]    10x64        (640)
#define WS_ZQ    9728     // ZQ[n][c][k] 10x4x64      (2560)
#define WS_WVUQ  12288    // WVuQ[n][e][k] 10x64x64   (40960)
#define WS_W2N   53248    // W2N[p][n][k][e] 3x10x64x64 (122880) -> end 176128 (705 KB)

typedef float v2f __attribute__((ext_vector_type(2)));

// Broadcast-free packed FMA via VOP3P op_sel (bit-identical IEEE fp32 fma),
// R7-proven; keeps the deep-prefetch gemm spill-free at the 128-VGPR cap.
#define PKFMA_LO(acc_, ap_, wp_) \
    asm("v_pk_fma_f32 %0, %1, %2, %0 op_sel:[0,0,0] op_sel_hi:[0,1,1]" \
        : "+v"(acc_) : "v"(ap_), "v"(wp_))
#define PKFMA_HI(acc_, ap_, wp_) \
    asm("v_pk_fma_f32 %0, %1, %2, %0 op_sel:[1,0,0] op_sel_hi:[1,1,1]" \
        : "+v"(acc_) : "v"(ap_), "v"(wp_))

// Wave-synchronous LDS fence (R8/R13-validated): sufficient for same-wave
// LDS RAW deps; replaces __syncthreads inside the wave-local attention chain.
#define WSYNC() do { __builtin_amdgcn_wave_barrier(); \
    asm volatile("s_waitcnt lgkmcnt(0)" ::: "memory"); \
    __builtin_amdgcn_wave_barrier(); } while (0)

// ---------------- pre-kernel (once per launch, into d_ws) -------------------
// R17: flattened to 91 dependency-free blocks (R16's single heavy block-0
// serial chain + 40 workers tracked the growing bench-vs-rocprof gap).
//   bid 0      : POS (fp64, reference-exact) + LW + PW + PQ (POS in LDS)
//   bid 1..10  : LQ[n]   (256 dots K=128, 1/thread)
//   bid 11..20 : WVuQ[n] (R15 fold)
//   bid 21..50 : W2N[p][n] (R16 fold)
//   bid 51..90 : per-(n,c) chain P2row -> Zrow -> {ZW,ZQ} entirely in LDS
// All table formulas identical to R16 (numerically validated).
__global__ void pre_kernel(float* __restrict__ ws,
                           const float* __restrict__ L_w,
                           const float* __restrict__ WQ,
                           const float* __restrict__ WK,
                           const float* __restrict__ WVd,
                           const float* __restrict__ qin2,
                           const float* __restrict__ qout2,
                           const float* __restrict__ UL_w,
                           const float* __restrict__ WVu2,
                           const float* __restrict__ qin1,
                           const float* __restrict__ WVu,
                           const float* __restrict__ qout1,
                           const float* __restrict__ WQ2,
                           const float* __restrict__ WK2,
                           const float* __restrict__ WVd2) {
    const int tid = threadIdx.x;
    const int bid = blockIdx.x;

    if (bid == 0) {
        __shared__ float sPOS[TS * TD];
        for (int idx = tid; idx < TS * TD; idx += 256) {
            int n = idx / TD, d = idx % TD;
            int j = d >> 1;
            double ang = (double)n / pow(1000.0, 2.0 * (double)j / (double)TD);
            float v = (float)((d & 1) ? cos(ang) : sin(ang));
            sPOS[idx] = v;
            ws[WS_POS + idx] = v;
        }
        __syncthreads();
        // LW[p][c][e]
        for (int idx = tid; idx < 3 * 4 * TE; idx += 256) {
            int p = idx >> 8, r = idx & 255, c = r >> 6, e = r & 63;
            const float* Wp = (p == 0 ? WQ : (p == 1 ? WK : WVd));
            const float* lr = L_w + c * TD;
            float acc = 0.f;
            for (int d = 0; d < TD; d++) acc = fmaf(lr[d], Wp[d * TE + e], acc);
            ws[WS_LW + idx] = acc;
        }
        // PW[p][n][e]
        for (int idx = tid; idx < 3 * TS * TE; idx += 256) {
            int p = idx / 640, r = idx % 640, n = r >> 6, e = r & 63;
            const float* Wp = (p == 0 ? WQ : (p == 1 ? WK : WVd));
            const float* pr = sPOS + n * TD;
            float acc = 0.f;
            for (int d = 0; d < TD; d++) acc = fmaf(pr[d], Wp[d * TE + e], acc);
            ws[WS_PW + idx] = acc;
        }
        // PQ[n][k]
        for (int idx = tid; idx < TS * TE; idx += 256) {
            int n = idx >> 6, k = idx & 63;
            const float* pr = sPOS + n * TD;
            const float* qp = qin1 + (size_t)n * TD * TE + k;
            float acc = 0.f;
            for (int d = 0; d < TD; d++) acc = fmaf(pr[d], qp[d * TE], acc);
            ws[WS_PQ + idx] = acc;
        }
        return;
    }
    if (bid <= 10) {   // LQ[n]
        int n = bid - 1;
        if (tid < 4 * TE) {
            int c = tid >> 6, k = tid & 63;
            const float* lr = L_w + c * TD;
            const float* qp = qin1 + (size_t)n * TD * TE + k;
            float acc = 0.f;
            for (int d = 0; d < TD; d++) acc = fmaf(lr[d], qp[d * TE], acc);
            ws[WS_LQ + n * 256 + tid] = acc;
        }
        return;
    }
    if (bid <= 20) {   // WVuQ[n]
        int n = bid - 11;
        float* dst = ws + WS_WVUQ + n * 4096;
        for (int idx = tid; idx < TE * TE; idx += 256) {
            int e = idx >> 6, k = idx & 63;
            const float* wv = WVu + (size_t)e * TD;
            const float* qp = qin1 + (size_t)n * TD * TE + k;
            float acc = 0.f;
            for (int d = 0; d < TD; d++) acc = fmaf(wv[d], qp[d * TE], acc);
            dst[idx] = acc;
        }
        return;
    }
    if (bid <= 50) {   // W2N[p][n]
        int p = (bid - 21) / 10, n = (bid - 21) % 10;
        const float* Wp = (p == 0 ? WQ2 : (p == 1 ? WK2 : WVd2));
        float* dst = ws + WS_W2N + ((p * 10 + n) << 12);
        for (int idx = tid; idx < TE * TE; idx += 256) {
            int k = idx >> 6, e = idx & 63;
            const float* qp = qout1 + ((size_t)n * TE + k) * TD;
            float acc = 0.f;
            for (int j = 0; j < TD; j += 4) {
                float4 q4 = *(const float4*)(qp + j);
                acc = fmaf(q4.x, Wp[(j + 0) * TE + e], acc);
                acc = fmaf(q4.y, Wp[(j + 1) * TE + e], acc);
                acc = fmaf(q4.z, Wp[(j + 2) * TE + e], acc);
                acc = fmaf(q4.w, Wp[(j + 3) * TE + e], acc);
            }
            dst[idx] = acc;
        }
        return;
    }
    // bid 51..90: (n,c) chain: P2 row -> Z row -> ZW + ZQ rows
    {
        int t = bid - 51, n = t >> 2, c = t & 3;
        __shared__ float sP2r[TE];    // P2[n][c][:]
        __shared__ float sZr[TD];     // Z[n][c][:]
        if (tid < TE) {   // P2[n][c][i] = sum_d qout2[n][i][d]*UL_w[d][c]
            int i = tid;
            const float* qp = qout2 + ((size_t)n * TE + i) * TD;
            float acc = 0.f;
            for (int d = 0; d < TD; d += 4) {
                float4 q4 = *(const float4*)(qp + d);
                acc = fmaf(q4.x, UL_w[(d + 0) * 4 + c], acc);
                acc = fmaf(q4.y, UL_w[(d + 1) * 4 + c], acc);
                acc = fmaf(q4.z, UL_w[(d + 2) * 4 + c], acc);
                acc = fmaf(q4.w, UL_w[(d + 3) * 4 + c], acc);
            }
            sP2r[i] = acc;
        }
        __syncthreads();
        if (tid < TD) {   // Z[n][c][j] = sum_i qin2[n][j][i]*P2[n][c][i]
            int j = tid;
            const float* ip = qin2 + ((size_t)n * TD + j) * TE;
            float acc = 0.f;
            for (int i = 0; i < TE; i += 4) {
                float4 q4 = *(const float4*)(ip + i);
                acc = fmaf(q4.x, sP2r[i + 0], acc);
                acc = fmaf(q4.y, sP2r[i + 1], acc);
                acc = fmaf(q4.z, sP2r[i + 2], acc);
                acc = fmaf(q4.w, sP2r[i + 3], acc);
            }
            sZr[j] = acc;
        }
        __syncthreads();
        if (tid < TE) {   // ZW[n][c][e] = sum_j WVu2[e][j]*Z[n][c][j]
            int e = tid;
            const float* wp = WVu2 + (size_t)e * TD;
            float acc = 0.f;
            for (int j = 0; j < TD; j += 4) {
                float4 w4 = *(const float4*)(wp + j);
                acc = fmaf(w4.x, sZr[j + 0], acc);
                acc = fmaf(w4.y, sZr[j + 1], acc);
                acc = fmaf(w4.z, sZr[j + 2], acc);
                acc = fmaf(w4.w, sZr[j + 3], acc);
            }
            ws[WS_ZW + (n * 4 + c) * TE + e] = acc;
        } else if (tid < 2 * TE) {   // ZQ[n][c][k] = sum_j qout1[n][k][j]*Z[n][c][j]
            int k = tid - TE;
            const float* qp = qout1 + ((size_t)n * TE + k) * TD;
            float acc = 0.f;
            for (int j = 0; j < TD; j += 4) {
                float4 q4 = *(const float4*)(qp + j);
                acc = fmaf(q4.x, sZr[j + 0], acc);
                acc = fmaf(q4.y, sZr[j + 1], acc);
                acc = fmaf(q4.z, sZr[j + 2], acc);
                acc = fmaf(q4.w, sZr[j + 3], acc);
            }
            ws[WS_ZQ + (n * 4 + c) * TE + k] = acc;
        }
    }
}

// ---------------- M-row x C-col fp32 GEMM tile, packed-pair FMAs ------------
// Deep W-prefetch (R5/R6) + op_sel pk-fma (R7): spill-free at cap 128.
template <int M, int SPLIT, int C, int K, bool ADD>
__device__ __forceinline__ void gemm_f32(
    const float* __restrict__ Ap, int a0, int aHi, int aLo,
    const float* __restrict__ W, int ws,
    float* __restrict__ Op, int o0, int oHi, int oLo,
    float scale)
{
    static_assert(C % 4 == 0, "C must be a multiple of 4");
    static_assert(K % 16 == 0 && K >= 32, "K must be a multiple of 16, >=32");
    constexpr int CG = C / 4;   // float4 groups
    constexpr int CP = C / 2;   // float2 pairs
    v2f acc[M][CP];
#pragma unroll
    for (int m = 0; m < M; m++)
#pragma unroll
        for (int p = 0; p < CP; p++) acc[m][p] = (v2f)(0.f);

    float4 aR0[M], aR1[M];
    float4 wA[8 * CG], wB[8 * CG];      // ping-pong 8-k W buffers
    const float* ap = Ap + a0;
    const float* wp = W;

    auto loadW8 = [&](float4* wR, const float* w) {
#pragma unroll
        for (int kk = 0; kk < 8; kk++)
#pragma unroll
            for (int cg = 0; cg < CG; cg++)
                wR[kk * CG + cg] = *(const float4*)(w + kk * ws + cg * 4);
    };
    auto loadA = [&](float4* aR, const float* a) {
#pragma unroll
        for (int m = 0; m < M; m++)
            aR[m] = *(const float4*)(a + (m / SPLIT) * aHi + (m % SPLIT) * aLo);
    };
    auto computeH = [&](const float4* aR, const float4* wR) {
#pragma unroll
        for (int m = 0; m < M; m++) {
            const v2f* ap2 = (const v2f*)&aR[m];    // (a0,a1),(a2,a3)
#pragma unroll
            for (int kp = 0; kp < 2; kp++) {
                const v2f* wf0 = (const v2f*)&wR[(2 * kp + 0) * CG];
                const v2f* wf1 = (const v2f*)&wR[(2 * kp + 1) * CG];
#pragma unroll
                for (int p = 0; p < CP; p++) {
                    PKFMA_LO(acc[m][p], ap2[kp], wf0[p]);   // k = 2kp
                    PKFMA_HI(acc[m][p], ap2[kp], wf1[p]);   // k = 2kp+1
                }
            }
        }
    };

    loadW8(wA, wp);
    loadA(aR0, ap);
#pragma unroll 1
    for (int k = 0; k + 16 < K; k += 16) {
        loadW8(wB, wp + 8 * ws);
        loadA(aR1, ap + 4);
        computeH(aR0, wA);
        loadA(aR0, ap + 8);
        computeH(aR1, wA + 4 * CG);
        loadW8(wA, wp + 16 * ws);
        loadA(aR1, ap + 12);
        computeH(aR0, wB);
        loadA(aR0, ap + 16);
        computeH(aR1, wB + 4 * CG);
        wp += 16 * ws; ap += 16;
    }
    loadW8(wB, wp + 8 * ws);
    loadA(aR1, ap + 4);
    computeH(aR0, wA);
    loadA(aR0, ap + 8);
    computeH(aR1, wA + 4 * CG);
    loadA(aR1, ap + 12);
    computeH(aR0, wB);
    computeH(aR1, wB + 4 * CG);

    v2f s2; s2.x = scale; s2.y = scale;
#pragma unroll
    for (int m = 0; m < M; m++) {
        float* op = Op + o0 + (m / SPLIT) * oHi + (m % SPLIT) * oLo;
#pragma unroll
        for (int cg = 0; cg < CG; cg++) {
            float4 r;
            v2f* rp = (v2f*)&r;
            if constexpr (ADD) {
                float4 v = *(float4*)(op + cg * 4);
                const v2f* vp = (const v2f*)&v;
                rp[0] = s2 * acc[m][cg * 2 + 0] + vp[0];
                rp[1] = s2 * acc[m][cg * 2 + 1] + vp[1];
            } else {
                rp[0] = s2 * acc[m][cg * 2 + 0];
                rp[1] = s2 * acc[m][cg * 2 + 1];
            }
            *(float4*)(op + cg * 4) = r;
        }
    }
}

// ---------------- fused kernel ----------------------------------------------
// Identical to R16 (461us steady, proven): rank-64 layer-2 collapse
// (QKV-l2 = t1@W2N K=64; quesout1 deleted; out = t1.ZQ + s*G2.ZW),
// rank-4 layer-1 QKV, qin1 fold (t1 = x@LQ + PQ + s*G1@WVuQ),
// wave-local attention chains with WSYNC.
// BT=8, 78.72 KB LDS -> 2 WG/CU; VGPR<=128 (cliff at 128/129, R5);
// launch_bounds(256,2) pins the cap (R0/R6/R7/R10/R11-proven).
extern "C" __global__ __launch_bounds__(NTHR, 2)
void trans_fused(const float* __restrict__ x,
                 const float* __restrict__ L_w, const float* __restrict__ UL_w,
                 const float* __restrict__ WQ,  const float* __restrict__ WK,
                 const float* __restrict__ WVd, const float* __restrict__ WVu,
                 const float* __restrict__ WQ2, const float* __restrict__ WK2,
                 const float* __restrict__ WVd2,const float* __restrict__ WVu2,
                 const float* __restrict__ qin1,const float* __restrict__ qout1,
                 const float* __restrict__ qin2,const float* __restrict__ qout2,
                 const float* __restrict__ POSb, float* __restrict__ out)
{
    extern __shared__ float lds[];
    float* Hs = lds;                      // [80][HSTR]; t1 in cols 0..63 (persistent)
    float* Qb = lds + HS_FLOATS;          // [40][QSTR]; Q then G (per hb)
    float* Kb = Qb + BUF_FLOATS;          // [40][QSTR]
    float* Vb = Kb + BUF_FLOATS;          // [40][QSTR] Vd
    float* Pb = Vb + BUF_FLOATS;          // [8][10][12] logits -> softmax weights

    const int tid = threadIdx.x;
    const int vtid = (tid + ((blockIdx.x & 3) << 6)) & 255;  // rotate idle windows
    const int w = vtid >> 6;              // wave-local batch index b4 (wave-aligned)
    const int l = vtid & 63;
    const int gb0 = blockIdx.x * BT;
    const float* LWb   = POSb + WS_LW;
    const float* PWb   = POSb + WS_PW;
    const float* ZWb   = POSb + WS_ZW;
    const float* LQb   = POSb + WS_LQ;
    const float* PQb   = POSb + WS_PQ;
    const float* ZQb   = POSb + WS_ZQ;
    const float* WVuQb = POSb + WS_WVUQ;
    const float* W2Nb  = POSb + WS_W2N;

    // ================= LAYER 1 (h never materialized) =================
    for (int hb = 0; hb < 2; ++hb) {
        // ---- QKV-l1 rank-4 (1920 tasks) + t1base = x@LQ + PQ (640 tasks) ----
        for (int t = vtid; t < 2560; t += NTHR) {
            if (t < 1920) {
                int p = t / 640, r2 = t % 640, rr = r2 >> 4, e4 = r2 & 15;
                int b4 = rr / 10, n = rr - b4 * 10;
                const float* xp = x + ((size_t)(gb0 + hb * 4 + b4) * TS + n) * 4;
                float4 x4 = *(const float4*)xp;
                const float* xf = (const float*)&x4;
                const float* lw = LWb + p * 256 + e4 * 4;
                float4 pw = *(const float4*)(PWb + p * 640 + n * 64 + e4 * 4);
                v2f a0 = ((const v2f*)&pw)[0], a1 = ((const v2f*)&pw)[1];
#pragma unroll
                for (int c = 0; c < 4; c++) {
                    float4 l4 = *(const float4*)(lw + c * 64);
                    v2f xb; xb.x = xf[c]; xb.y = xf[c];
                    a0 = xb * ((const v2f*)&l4)[0] + a0;
                    a1 = xb * ((const v2f*)&l4)[1] + a1;
                }
                float* Ob = (p == 0 ? Qb : (p == 1 ? Kb : Vb));
                float4 r4;
                ((v2f*)&r4)[0] = a0; ((v2f*)&r4)[1] = a1;
                *(float4*)(Ob + rr * QSTR + e4 * 4) = r4;
            } else {
                int t2 = t - 1920;              // 0..639
                int rr = t2 >> 4, cg = t2 & 15;
                int b4 = rr / 10, n = rr - b4 * 10;
                const float* xp = x + ((size_t)(gb0 + hb * 4 + b4) * TS + n) * 4;
                float4 x4 = *(const float4*)xp;
                const float* xf = (const float*)&x4;
                const float* lq = LQb + n * 256 + cg * 4;
                float4 pq = *(const float4*)(PQb + n * 64 + cg * 4);
                v2f a0 = ((const v2f*)&pq)[0], a1 = ((const v2f*)&pq)[1];
#pragma unroll
                for (int c = 0; c < 4; c++) {
                    float4 l4 = *(const float4*)(lq + c * 64);
                    v2f xb; xb.x = xf[c]; xb.y = xf[c];
                    a0 = xb * ((const v2f*)&l4)[0] + a0;
                    a1 = xb * ((const v2f*)&l4)[1] + a1;
                }
                float4 r4;
                ((v2f*)&r4)[0] = a0; ((v2f*)&r4)[1] = a1;
                *(float4*)(Hs + (hb * 40 + rr) * HSTR + cg * 4) = r4;
            }
        }
        __syncthreads();

        // ---- logits: 55 (i,j<=i) pairs, one lane each; own batch ----
        if (l < 55) {
            int i = 0, base = 0, pr = l;
            while (pr >= base + i + 1) { base += i + 1; i++; }
            int j = pr - base;
            const float* qr = Qb + (w * 10 + i) * QSTR;
            const float* kr = Kb + (w * 10 + j) * QSTR;
            v2f s0 = (v2f)(0.f), s1 = (v2f)(0.f);
            for (int e = 0; e < TE; e += 8) {
                float4 qa = *(const float4*)(qr + e);
                float4 ka = *(const float4*)(kr + e);
                float4 qc = *(const float4*)(qr + e + 4);
                float4 kc = *(const float4*)(kr + e + 4);
                s0 = ((const v2f*)&qa)[0] * ((const v2f*)&ka)[0] + s0;
                s1 = ((const v2f*)&qa)[1] * ((const v2f*)&ka)[1] + s1;
                s0 = ((const v2f*)&qc)[0] * ((const v2f*)&kc)[0] + s0;
                s1 = ((const v2f*)&qc)[1] * ((const v2f*)&kc)[1] + s1;
            }
            Pb[(hb * 4 + w) * 120 + i * 12 + j] = (s0.x + s0.y) + (s1.x + s1.y);
        }
        WSYNC();

        // ---- softmax over keys j<=i (own batch) ----
        if (l < TS) {
            float* pr = Pb + (hb * 4 + w) * 120 + l * 12;
            float m = pr[0];
#pragma unroll
            for (int j = 1; j < TS; j++) if (j <= l) m = fmaxf(m, pr[j]);
            float sum = 0.f;
#pragma unroll
            for (int j = 0; j < TS; j++) if (j <= l) { float e = expf(pr[j] - m); pr[j] = e; sum += e; }
#pragma unroll
            for (int j = 0; j < TS; j++) pr[j] = (j <= l) ? pr[j] / sum : 0.f;
        }
        WSYNC();

        // ---- G[q][e] (own batch): 160 tasks per wave; into Qb (Q dead) ----
        for (int oi = l; oi < 160; oi += 64) {
            int q = oi >> 4, e4 = (oi & 15) * 4;
            const float* pp = Pb + (hb * 4 + w) * 120 + q * 12;
            v2f g0 = (v2f)(0.f), g1 = (v2f)(0.f);
#pragma unroll
            for (int k = 0; k < TS; k++) {
                float p = pp[k];
                v2f pv; pv.x = p; pv.y = p;
                float4 v = *(const float4*)(Vb + (w * 10 + k) * QSTR + e4);
                g0 = pv * ((const v2f*)&v)[0] + g0;
                g1 = pv * ((const v2f*)&v)[1] + g1;
            }
            float4 g;
            ((v2f*)&g)[0] = g0; ((v2f*)&g)[1] = g1;
            *(float4*)(Qb + (w * 10 + q) * QSTR + e4) = g;
        }
        __syncthreads();   // t1gemm groups rows across waves (M=4 over b4)

        // ---- t1 += s * G @ WVuQ[n]: 160 tasks = n(10) x cg(16), M=4, K=64 ----
        if (vtid < 160) {
            int n = vtid >> 4, cg = vtid & 15;
            gemm_f32<4, 1, 4, TE, true>(
                Qb, n * QSTR, 10 * QSTR, 0,
                WVuQb + n * 4096 + cg * 4, TE,
                Hs, (hb * 40 + n) * HSTR + cg * 4, 10 * HSTR, 0,
                INVSQRT10);
        }
        __syncthreads();
    } // hb layer 1

    // ================= LAYER 2 (rank-64 collapsed; t1 stays in Hs) ==========
    for (int hb = 0; hb < 2; ++hb) {
        // ---- QKV-l2: Q2/K2/V2 = t1 @ W2N[p][n]; 480 tasks, M=4, K=64 ----
        for (int t = vtid; t < 480; t += NTHR) {
            int p = t / 160, rem = t - p * 160, n = rem >> 4, cg = rem & 15;
            float* Ob = (p == 0 ? Qb : (p == 1 ? Kb : Vb));
            gemm_f32<4, 1, 4, TE, false>(
                Hs, (hb * 40 + n) * HSTR, 10 * HSTR, 0,
                W2Nb + ((p * 10 + n) << 12) + cg * 4, TE,
                Ob, n * QSTR + cg * 4, 10 * QSTR, 0, 1.f);
        }
        __syncthreads();

        // ---- logits2 (wave-local) ----
        if (l < 55) {
            int i = 0, base = 0, pr = l;
            while (pr >= base + i + 1) { base += i + 1; i++; }
            int j = pr - base;
            const float* qr = Qb + (w * 10 + i) * QSTR;
            const float* kr = Kb + (w * 10 + j) * QSTR;
            v2f s0 = (v2f)(0.f), s1 = (v2f)(0.f);
            for (int e = 0; e < TE; e += 8) {
                float4 qa = *(const float4*)(qr + e);
                float4 ka = *(const float4*)(kr + e);
                float4 qc = *(const float4*)(qr + e + 4);
                float4 kc = *(const float4*)(kr + e + 4);
                s0 = ((const v2f*)&qa)[0] * ((const v2f*)&ka)[0] + s0;
                s1 = ((const v2f*)&qa)[1] * ((const v2f*)&ka)[1] + s1;
                s0 = ((const v2f*)&qc)[0] * ((const v2f*)&kc)[0] + s0;
                s1 = ((const v2f*)&qc)[1] * ((const v2f*)&kc)[1] + s1;
            }
            Pb[(hb * 4 + w) * 120 + i * 12 + j] = (s0.x + s0.y) + (s1.x + s1.y);
        }
        WSYNC();

        // ---- softmax2 (own batch) ----
        if (l < TS) {
            float* pr = Pb + (hb * 4 + w) * 120 + l * 12;
            float m = pr[0];
#pragma unroll
            for (int j = 1; j < TS; j++) if (j <= l) m = fmaxf(m, pr[j]);
            float sum = 0.f;
#pragma unroll
            for (int j = 0; j < TS; j++) if (j <= l) { float e = expf(pr[j] - m); pr[j] = e; sum += e; }
#pragma unroll
            for (int j = 0; j < TS; j++) pr[j] = (j <= l) ? pr[j] / sum : 0.f;
        }
        WSYNC();

        // ---- G2[q][e] (own batch): 160 tasks/wave; into Qb (Q2 dead) ----
        for (int oi = l; oi < 160; oi += 64) {
            int q = oi >> 4, e4 = (oi & 15) * 4;
            const float* pp = Pb + (hb * 4 + w) * 120 + q * 12;
            v2f g0 = (v2f)(0.f), g1 = (v2f)(0.f);
#pragma unroll
            for (int k = 0; k < TS; k++) {
                float p = pp[k];
                v2f pv; pv.x = p; pv.y = p;
                float4 v = *(const float4*)(Vb + (w * 10 + k) * QSTR + e4);
                g0 = pv * ((const v2f*)&v)[0] + g0;
                g1 = pv * ((const v2f*)&v)[1] + g1;
            }
            float4 g;
            ((v2f*)&g)[0] = g0; ((v2f*)&g)[1] = g1;
            *(float4*)(Qb + (w * 10 + q) * QSTR + e4) = g;
        }
        WSYNC();

        // ---- out-fold: out[b][n][c] = t1.ZQ[n][c] + s * G2.ZW[n][c] ----
        if (l < 40) {
            int n = l >> 2, c = l & 3;
            const float* tr = Hs + (hb * 40 + w * 10 + n) * HSTR;   // t1 row
            const float* zq = ZQb + (n * 4 + c) * TE;
            v2f s0 = (v2f)(0.f), s1 = (v2f)(0.f);
            for (int k = 0; k < TE; k += 8) {
                float4 ta = *(const float4*)(tr + k);
                float4 za = *(const float4*)(zq + k);
                float4 tc = *(const float4*)(tr + k + 4);
                float4 zc = *(const float4*)(zq + k + 4);
                s0 = ((const v2f*)&ta)[0] * ((const v2f*)&za)[0] + s0;
                s1 = ((const v2f*)&ta)[1] * ((const v2f*)&za)[1] + s1;
                s0 = ((const v2f*)&tc)[0] * ((const v2f*)&zc)[0] + s0;
                s1 = ((const v2f*)&tc)[1] * ((const v2f*)&zc)[1] + s1;
            }
            float base = (s0.x + s0.y) + (s1.x + s1.y);
            const float* gr = Qb + (w * 10 + n) * QSTR;
            const float* zw = ZWb + (n * 4 + c) * TE;
            v2f a0 = (v2f)(0.f), a1 = (v2f)(0.f);
            for (int e = 0; e < TE; e += 8) {
                float4 ga = *(const float4*)(gr + e);
                float4 za = *(const float4*)(zw + e);
                float4 gc = *(const float4*)(gr + e + 4);
                float4 zc = *(const float4*)(zw + e + 4);
                a0 = ((const v2f*)&ga)[0] * ((const v2f*)&za)[0] + a0;
                a1 = ((const v2f*)&ga)[1] * ((const v2f*)&za)[1] + a1;
                a0 = ((const v2f*)&gc)[0] * ((const v2f*)&zc)[0] + a0;
                a1 = ((const v2f*)&gc)[1] * ((const v2f*)&zc)[1] + a1;
            }
            float att = (a0.x + a0.y) + (a1.x + a1.y);
            out[((size_t)(gb0 + hb * 4 + w) * TS + n) * 4 + c] =
                base + att * INVSQRT10;
        }
        __syncthreads();
    } // hb layer 2
}

// ---------------- host launch -----------------------------------------------
extern "C" void kernel_launch(void* const* d_in, const int* in_sizes, int n_in,
                              void* d_out, int out_size, void* d_ws, size_t ws_size,
                              hipStream_t stream) {
    const float* x    = (const float*)d_in[0];
    const float* L_w  = (const float*)d_in[1];
    const float* UL_w = (const float*)d_in[2];
    const float* WQ   = (const float*)d_in[3];
    const float* WK   = (const float*)d_in[4];
    const float* WVd  = (const float*)d_in[5];
    const float* WVu  = (const float*)d_in[6];
    const float* WQ2  = (const float*)d_in[7];
    const float* WK2  = (const float*)d_in[8];
    const float* WVd2 = (const float*)d_in[9];
    const float* WVu2 = (const float*)d_in[10];
    const float* qin1 = (const float*)d_in[11];
    const float* qout1= (const float*)d_in[12];
    const float* qin2 = (const float*)d_in[13];
    const float* qout2= (const float*)d_in[14];
    float* out = (float*)d_out;
    float* POSb = (float*)d_ws;   // WS_* layout (705 KB)

    int B = in_sizes[0] / (TS * 4);
    size_t lds_bytes = (size_t)LDS_FLOATS * sizeof(float);

    (void)hipFuncSetAttribute((const void*)trans_fused,
                              hipFuncAttributeMaxDynamicSharedMemorySize,
                              (int)lds_bytes);

    pre_kernel<<<dim3(91), dim3(256), 0, stream>>>(
        POSb, L_w, WQ, WK, WVd, qin2, qout2, UL_w, WVu2, qin1, WVu,
        qout1, WQ2, WK2, WVd2);
    trans_fused<<<dim3(B / BT), dim3(NTHR), lds_bytes, stream>>>(
        x, L_w, UL_w, WQ, WK, WVd, WVu, WQ2, WK2, WVd2, WVu2,
        qin1, qout1, qin2, qout2, POSb, out);
}